// Round 3
// baseline (676.068 us; speedup 1.0000x reference)
//
#include <hip/hip_runtime.h>
#include <math.h>

typedef __attribute__((ext_vector_type(8))) short short8;
typedef __attribute__((ext_vector_type(4))) short short4v;
typedef __attribute__((ext_vector_type(4))) float floatx4;
typedef __attribute__((ext_vector_type(16))) float floatx16;

#define GLOBAL_AS __attribute__((address_space(1)))
#define LDS_AS __attribute__((address_space(3)))

__device__ __forceinline__ float bf2f(unsigned short u) {
    unsigned int x = ((unsigned int)u) << 16;
    return __builtin_bit_cast(float, x);
}
__device__ __forceinline__ unsigned short f2bf(float f) {
    unsigned int u = __builtin_bit_cast(unsigned int, f);
    u += 0x7fffu + ((u >> 16) & 1u);
    return (unsigned short)(u >> 16);
}

// ---------------------------------------------------------------------------
// Merged prep: weight transposes + token fp32->bf16.
// ---------------------------------------------------------------------------
struct WX {
    const float* src[10];
    unsigned long long dst[10];
    int r64[10];
    int cum[11];
};

__global__ __launch_bounds__(256) void prep_kernel(
    WX P, unsigned short* __restrict__ base,
    const float* __restrict__ ta, const float* __restrict__ tb,
    unsigned short* __restrict__ oa, unsigned short* __restrict__ ob)
{
    __shared__ unsigned short T[64][72];
    const int bx = blockIdx.x;
    if (bx >= P.cum[10]) {
        const int cb = bx - P.cum[10];
        const float* in = cb < 1024 ? ta : tb;
        unsigned short* out = cb < 1024 ? oa : ob;
        const size_t b0 = (size_t)(cb & 1023) * 8192;
        #pragma unroll
        for (int j = 0; j < 8; ++j) {
            const size_t i = b0 + (size_t)j * 1024 + threadIdx.x * 4;
            float4 f = *(const float4*)(in + i);
            unsigned short o[4] = {f2bf(f.x), f2bf(f.y), f2bf(f.z), f2bf(f.w)};
            *(uint2*)(out + i) = *(const uint2*)o;
        }
        return;
    }
    int w = 0;
    #pragma unroll
    for (int i = 0; i < 10; ++i) if (bx >= P.cum[i + 1]) w = i + 1;
    const int tix = bx - P.cum[w];
    const int R = P.r64[w] * 64;
    const int r0 = (tix >> 4) * 64, c0 = (tix & 15) * 64;
    const float* in = P.src[w];
    unsigned short* out = base + P.dst[w];
    const int t = threadIdx.x;
    {
        const int r = t >> 2, cc = (t & 3) * 16;
        const float* p = in + (size_t)(r0 + r) * 1024 + c0 + cc;
        #pragma unroll
        for (int j = 0; j < 16; j += 4) {
            float4 f = *(const float4*)(p + j);
            T[cc + j + 0][r] = f2bf(f.x);
            T[cc + j + 1][r] = f2bf(f.y);
            T[cc + j + 2][r] = f2bf(f.z);
            T[cc + j + 3][r] = f2bf(f.w);
        }
    }
    __syncthreads();
    {
        const int c = t >> 2, rr = (t & 3) * 16;
        unsigned short* q = out + (size_t)(c0 + c) * R + r0 + rr;
        *(uint4*)(q)     = *(const uint4*)(&T[c][rr]);
        *(uint4*)(q + 8) = *(const uint4*)(&T[c][rr + 8]);
    }
}

// ===========================================================================
// Shared GEMM core: 128x128 tile, BK=64, 32x32x16 MFMA (2x2 frags/wave),
// XOR-swizzled lane-linear LDS, global_load_lds width-16 staging.
// Wave tile 64x64: acc[mi][ni] = 32x32, operand-swapped:
//   D = mfma(Wfrag(A-op, rows=out cols), Xfrag(B-op, cols=out rows)).
// C/D: out-row m = lane&31; out-col n = rg*8 + (lane>>5)*4 + (reg&3), reg=rg*4+r.
// ===========================================================================
#define GEMM_CORE(A_, B_, Kdim)                                               \
    const int tid = threadIdx.x;                                              \
    const int wave = tid >> 6, lane = tid & 63;                               \
    const int l32 = lane & 31, hi = lane >> 5;                                \
    const int wm = (wave & 1) * 64, wn = (wave >> 1) * 64;                    \
    const int srow8 = lane >> 3, c8 = lane & 7;                               \
    const int scol = (c8 ^ srow8) * 8;                                        \
    floatx16 acc[2][2];                                                       \
    _Pragma("unroll")                                                         \
    for (int i = 0; i < 2; ++i)                                               \
        _Pragma("unroll")                                                     \
        for (int j = 0; j < 2; ++j)                                           \
            _Pragma("unroll")                                                 \
            for (int r = 0; r < 16; ++r) acc[i][j][r] = 0.f;                  \
    const unsigned short* pa[4];                                              \
    const unsigned short* pb[4];                                              \
    _Pragma("unroll")                                                         \
    for (int i = 0; i < 4; ++i) {                                             \
        pa[i] = (A_) + (size_t)(bm + i * 32 + wave * 8 + srow8) * (Kdim) + scol; \
        pb[i] = (B_) + (size_t)(bn + i * 32 + wave * 8 + srow8) * (Kdim) + scol; \
    }                                                                         \
    int aoff[2][4], boff[2][4];                                               \
    _Pragma("unroll")                                                         \
    for (int f = 0; f < 2; ++f)                                               \
        _Pragma("unroll")                                                     \
        for (int s = 0; s < 4; ++s) {                                         \
            const int cg = ((s * 2 + hi) ^ (l32 & 7)) * 8;                    \
            aoff[f][s] = (wm + f * 32 + l32) * 64 + cg;                       \
            boff[f][s] = (wn + f * 32 + l32) * 64 + cg;                       \
        }                                                                     \
    for (int k0 = 0; k0 < (Kdim); k0 += 64) {                                 \
        _Pragma("unroll")                                                     \
        for (int i = 0; i < 4; ++i) {                                         \
            __builtin_amdgcn_global_load_lds((const GLOBAL_AS void*)(pa[i] + k0), \
                (LDS_AS void*)(As + i * 2048 + wave * 512), 16, 0, 0);        \
            __builtin_amdgcn_global_load_lds((const GLOBAL_AS void*)(pb[i] + k0), \
                (LDS_AS void*)(Bs + i * 2048 + wave * 512), 16, 0, 0);        \
        }                                                                     \
        __syncthreads();                                                      \
        _Pragma("unroll")                                                     \
        for (int s = 0; s < 4; ++s) {                                         \
            short8 af[2], bf[2];                                              \
            _Pragma("unroll")                                                 \
            for (int f = 0; f < 2; ++f) {                                     \
                af[f] = *(const short8*)&As[aoff[f][s]];                      \
                bf[f] = *(const short8*)&Bs[boff[f][s]];                      \
            }                                                                 \
            _Pragma("unroll")                                                 \
            for (int mi = 0; mi < 2; ++mi)                                    \
                _Pragma("unroll")                                             \
                for (int ni = 0; ni < 2; ++ni)                                \
                    acc[mi][ni] = __builtin_amdgcn_mfma_f32_32x32x16_bf16(    \
                        bf[ni], af[mi], acc[mi][ni], 0, 0, 0);                \
        }                                                                     \
        __syncthreads();                                                      \
    }

// ---------------------------------------------------------------------------
// Generic GEMM: MODE 0 plain, MODE 2 exact GELU.
// ---------------------------------------------------------------------------
template <int MODE>
__global__ __launch_bounds__(256) void gemm_kernel(
    const unsigned short* __restrict__ A,
    const unsigned short* __restrict__ Wt,
    const float* __restrict__ bias,
    unsigned short* __restrict__ C,
    int N, int K)
{
    __shared__ unsigned short As[128 * 64];
    __shared__ unsigned short Bs[128 * 64];
    const int bm = blockIdx.x * 128, bn = blockIdx.y * 128;
    GEMM_CORE(A, Wt, K)

    #pragma unroll
    for (int mi = 0; mi < 2; ++mi) {
        const int m = bm + wm + mi * 32 + l32;
        #pragma unroll
        for (int ni = 0; ni < 2; ++ni) {
            #pragma unroll
            for (int rg = 0; rg < 4; ++rg) {
                const int n0 = bn + wn + ni * 32 + rg * 8 + hi * 4;
                float4 bv = *(const float4*)&bias[n0];
                float v[4];
                #pragma unroll
                for (int r = 0; r < 4; ++r)
                    v[r] = acc[mi][ni][rg * 4 + r] + ((const float*)&bv)[r];
                if (MODE == 2) {
                    #pragma unroll
                    for (int r = 0; r < 4; ++r)
                        v[r] = 0.5f * v[r] * (1.0f + erff(v[r] * 0.70710678118f));
                }
                unsigned short o[4] = {f2bf(v[0]), f2bf(v[1]), f2bf(v[2]), f2bf(v[3])};
                *(uint2*)&C[(size_t)m * N + n0] = *(const uint2*)o;
            }
        }
    }
}

// ---------------------------------------------------------------------------
// Merged output-projection GEMM for BOTH streams + residual (grid 64,16).
// ---------------------------------------------------------------------------
__global__ __launch_bounds__(256) void gemm_out_kernel(
    const unsigned short* __restrict__ A0, const unsigned short* __restrict__ W0,
    const float* __restrict__ bi0, const float* __restrict__ r0, unsigned short* __restrict__ C0,
    const unsigned short* __restrict__ A1, const unsigned short* __restrict__ W1,
    const float* __restrict__ bi1, const float* __restrict__ r1, unsigned short* __restrict__ C1)
{
    __shared__ unsigned short As[128 * 64];
    __shared__ unsigned short Bs[128 * 64];
    const int s1 = blockIdx.y >> 3;
    const unsigned short* A = s1 ? A1 : A0;
    const unsigned short* Wt = s1 ? W1 : W0;
    const float* bias = s1 ? bi1 : bi0;
    const float* resid = s1 ? r1 : r0;
    unsigned short* C = s1 ? C1 : C0;
    const int bm = blockIdx.x * 128, bn = (blockIdx.y & 7) * 128;
    GEMM_CORE(A, Wt, 1024)

    #pragma unroll
    for (int mi = 0; mi < 2; ++mi) {
        const int m = bm + wm + mi * 32 + l32;
        #pragma unroll
        for (int ni = 0; ni < 2; ++ni) {
            #pragma unroll
            for (int rg = 0; rg < 4; ++rg) {
                const int n0 = bn + wn + ni * 32 + rg * 8 + hi * 4;
                float4 bv = *(const float4*)&bias[n0];
                float4 rv = *(const float4*)&resid[(size_t)m * 1024 + n0];
                float v[4];
                v[0] = acc[mi][ni][rg * 4 + 0] + bv.x + rv.x;
                v[1] = acc[mi][ni][rg * 4 + 1] + bv.y + rv.y;
                v[2] = acc[mi][ni][rg * 4 + 2] + bv.z + rv.z;
                v[3] = acc[mi][ni][rg * 4 + 3] + bv.w + rv.w;
                unsigned short o[4] = {f2bf(v[0]), f2bf(v[1]), f2bf(v[2]), f2bf(v[3])};
                *(uint2*)&C[(size_t)m * 1024 + n0] = *(const uint2*)o;
            }
        }
    }
}

// ---------------------------------------------------------------------------
// Merged QKV GEMM for BOTH streams (grid 64,48). buf 0 (Q): pre-scaled.
// buf 2 (V): written in per-head transposed layout with d&8 half-swap.
// ---------------------------------------------------------------------------
__global__ __launch_bounds__(256) void gemm_qkv_kernel(
    const unsigned short* __restrict__ At, const unsigned short* __restrict__ Wt3t,
    const float* __restrict__ tb0, const float* __restrict__ tb1, const float* __restrict__ tb2,
    unsigned short* __restrict__ to0, unsigned short* __restrict__ to1, unsigned short* __restrict__ to2,
    const unsigned short* __restrict__ Af, const unsigned short* __restrict__ Wt3f,
    const float* __restrict__ fb0, const float* __restrict__ fb1, const float* __restrict__ fb2,
    unsigned short* __restrict__ fo0, unsigned short* __restrict__ fo1, unsigned short* __restrict__ fo2,
    float scale0)
{
    __shared__ unsigned short As[128 * 64];
    __shared__ unsigned short Bs[128 * 64];
    const int str = blockIdx.y >= 24;
    const unsigned short* A = str ? Af : At;
    const unsigned short* Wt = str ? Wt3f : Wt3t;
    const int byy = str ? (blockIdx.y - 24) : blockIdx.y;
    const int buf = byy >> 3;
    const int bn = byy * 128;
    const int cn = (byy & 7) * 128;
    const float* bias = str ? (buf == 0 ? fb0 : (buf == 1 ? fb1 : fb2))
                            : (buf == 0 ? tb0 : (buf == 1 ? tb1 : tb2));
    unsigned short* C = str ? (buf == 0 ? fo0 : (buf == 1 ? fo1 : fo2))
                            : (buf == 0 ? to0 : (buf == 1 ? to1 : to2));
    const float scale = buf == 0 ? scale0 : 1.0f;
    const int bm = blockIdx.x * 128;
    GEMM_CORE(A, Wt, 1024)

    #pragma unroll
    for (int mi = 0; mi < 2; ++mi) {
        const int m = bm + wm + mi * 32 + l32;
        #pragma unroll
        for (int ni = 0; ni < 2; ++ni) {
            #pragma unroll
            for (int rg = 0; rg < 4; ++rg) {
                const int n0 = cn + wn + ni * 32 + rg * 8 + hi * 4;
                float4 bv = *(const float4*)&bias[n0];
                unsigned short o[4];
                #pragma unroll
                for (int r = 0; r < 4; ++r)
                    o[r] = f2bf((acc[mi][ni][rg * 4 + r] + ((const float*)&bv)[r]) * scale);
                if (buf == 2) {
                    const int b = m >> 11, t = m & 2047;
                    const int h = n0 >> 6, d0 = n0 & 63;
                    const int tsw = t ^ ((d0 & 8) ? 4 : 0);
                    unsigned short* vb = C + ((size_t)(b * 16 + h) * 64) * 2048 + tsw;
                    #pragma unroll
                    for (int r = 0; r < 4; ++r) vb[(size_t)(d0 + r) * 2048] = o[r];
                } else {
                    *(uint2*)&C[(size_t)m * 1024 + n0] = *(const uint2*)o;
                }
            }
        }
    }
}

// ---------------------------------------------------------------------------
// Merged flash, flat grid 2048, XCD-clustered (all 16 q-tiles of one
// (stream,b,h) on one XCD). 128 q-rows/block, 64-key K-tile (16 KB LDS --
// the high-occupancy config; R1: reverted the R0 double-buffer, which cost
// occupancy (37->30%) for less than the latency it hid -- m99/m100 regime).
// Q pre-scaled by 0.125*log2e; S^T=mfma(K,Q); exp2 in-register.
// R1: P f32->bf16 pack via v_cvt_pk_bf16_f32 (1 op packs 2 values, replaces
// 4 int-adds + 2 perms per score-quad; RNE rounding). P^T feeds 16x16x16 PV;
// denominator via all-ones-A MFMA. Vt (d&8) halves pre-swapped.
// ---------------------------------------------------------------------------
__global__ __launch_bounds__(256) void flash_kernel(
    const unsigned short* __restrict__ Q0, const unsigned short* __restrict__ K0,
    const unsigned short* __restrict__ V0, unsigned short* __restrict__ O0,
    const unsigned short* __restrict__ Q1, const unsigned short* __restrict__ K1,
    const unsigned short* __restrict__ V1, unsigned short* __restrict__ O1)
{
    __shared__ unsigned short Ks[64 * 64];
    __shared__ unsigned short Vs[64 * 64];

    const int bid = blockIdx.x;
    const int p = (bid & 7) * 16 + (bid >> 7);
    const int qt = (bid >> 3) & 15;
    const int s1 = p >= 64;
    const int rem = p & 63;
    const int b = rem >> 4, h = rem & 15;
    const unsigned short* Q = s1 ? Q1 : Q0;
    const unsigned short* Kmat = s1 ? K1 : K0;
    const unsigned short* Vtp = s1 ? V1 : V0;
    unsigned short* O = s1 ? O1 : O0;
    const int q0 = qt * 128;

    const int tid = threadIdx.x;
    const int wave = tid >> 6, lane = tid & 63;
    const int quad = lane >> 4, l16 = lane & 15;

    const unsigned short* qp = Q + (size_t)(b * 2048 + q0 + wave * 32 + l16) * 1024 + h * 64;
    short8 qf[2][2];
    qf[0][0] = *(const short8*)(qp + quad * 8);
    qf[0][1] = *(const short8*)(qp + 32 + quad * 8);
    qf[1][0] = *(const short8*)(qp + 16 * 1024 + quad * 8);
    qf[1][1] = *(const short8*)(qp + 16 * 1024 + 32 + quad * 8);

    const int srow8 = lane >> 3;
    const int c8 = lane & 7;
    const int rit0 = wave * 16 + srow8;
    const int rit1 = rit0 + 8;
    const int col0 = (c8 ^ (rit0 & 7)) * 8;
    const int col1 = (c8 ^ (rit1 & 7)) * 8;
    const unsigned short* kbase = Kmat + (size_t)b * 2048 * 1024 + h * 64;
    const unsigned short* vbase = Vtp + (size_t)(b * 16 + h) * 64 * 2048;
    unsigned short* lk0 = Ks + (wave * 16) * 64;
    unsigned short* lk1 = lk0 + 8 * 64;
    unsigned short* lv0 = Vs + (wave * 16) * 64;
    unsigned short* lv1 = lv0 + 8 * 64;

    int koff[4][2];
    #pragma unroll
    for (int nt = 0; nt < 4; ++nt)
        #pragma unroll
        for (int hh = 0; hh < 2; ++hh)
            koff[nt][hh] = (nt * 16 + l16) * 64 + (((hh * 4 + quad) ^ (l16 & 7)) * 8);
    int voff[4][4];
    #pragma unroll
    for (int dt = 0; dt < 4; ++dt)
        #pragma unroll
        for (int nt = 0; nt < 4; ++nt)
            voff[dt][nt] = (dt * 16 + l16) * 64 +
                           (((nt * 2 + (quad >> 1)) ^ (l16 & 7)) * 8) +
                           (((quad & 1) ^ (l16 >> 3)) * 4);

    floatx4 oa[2][4], la[2];
    #pragma unroll
    for (int qg = 0; qg < 2; ++qg) {
        la[qg] = (floatx4){0.f, 0.f, 0.f, 0.f};
        #pragma unroll
        for (int dt = 0; dt < 4; ++dt) oa[qg][dt] = (floatx4){0.f, 0.f, 0.f, 0.f};
    }
    const short4v vone = {(short)0x3F80, (short)0x3F80, (short)0x3F80, (short)0x3F80};

    for (int kt = 0; kt < 32; ++kt) {
        const unsigned short* kg0 = kbase + (size_t)(kt * 64 + rit0) * 1024 + col0;
        const unsigned short* kg1 = kbase + (size_t)(kt * 64 + rit1) * 1024 + col1;
        const unsigned short* vg0 = vbase + (size_t)rit0 * 2048 + kt * 64 + col0;
        const unsigned short* vg1 = vbase + (size_t)rit1 * 2048 + kt * 64 + col1;
        __builtin_amdgcn_global_load_lds((const GLOBAL_AS void*)kg0, (LDS_AS void*)lk0, 16, 0, 0);
        __builtin_amdgcn_global_load_lds((const GLOBAL_AS void*)kg1, (LDS_AS void*)lk1, 16, 0, 0);
        __builtin_amdgcn_global_load_lds((const GLOBAL_AS void*)vg0, (LDS_AS void*)lv0, 16, 0, 0);
        __builtin_amdgcn_global_load_lds((const GLOBAL_AS void*)vg1, (LDS_AS void*)lv1, 16, 0, 0);
        __syncthreads();

        short4v pf[2][4];
        #pragma unroll
        for (int nt = 0; nt < 4; ++nt) {
            short8 k0 = *(const short8*)&Ks[koff[nt][0]];
            short8 k1 = *(const short8*)&Ks[koff[nt][1]];
            #pragma unroll
            for (int qg = 0; qg < 2; ++qg) {
                floatx4 s = (floatx4){0.f, 0.f, 0.f, 0.f};
                s = __builtin_amdgcn_mfma_f32_16x16x32_bf16(k0, qf[qg][0], s, 0, 0, 0);
                s = __builtin_amdgcn_mfma_f32_16x16x32_bf16(k1, qf[qg][1], s, 0, 0, 0);
                float p0 = __builtin_amdgcn_exp2f(s[0]);
                float p1 = __builtin_amdgcn_exp2f(s[1]);
                float p2 = __builtin_amdgcn_exp2f(s[2]);
                float p3 = __builtin_amdgcn_exp2f(s[3]);
                union { unsigned u[2]; short4v s4; } pk;
                asm("v_cvt_pk_bf16_f32 %0, %1, %2"
                    : "=v"(pk.u[0]) : "v"(p0), "v"(p1));
                asm("v_cvt_pk_bf16_f32 %0, %1, %2"
                    : "=v"(pk.u[1]) : "v"(p2), "v"(p3));
                pf[qg][nt] = pk.s4;
                la[qg] = __builtin_amdgcn_mfma_f32_16x16x16bf16_1k(vone, pf[qg][nt], la[qg], 0, 0, 0);
            }
        }
        #pragma unroll
        for (int dt = 0; dt < 4; ++dt)
            #pragma unroll
            for (int nt = 0; nt < 4; ++nt) {
                short4v vf = *(const short4v*)&Vs[voff[dt][nt]];
                oa[0][dt] = __builtin_amdgcn_mfma_f32_16x16x16bf16_1k(vf, pf[0][nt], oa[0][dt], 0, 0, 0);
                oa[1][dt] = __builtin_amdgcn_mfma_f32_16x16x16bf16_1k(vf, pf[1][nt], oa[1][dt], 0, 0, 0);
            }
        __syncthreads();
    }

    #pragma unroll
    for (int qg = 0; qg < 2; ++qg) {
        const float linv = 1.0f / la[qg][0];
        unsigned short* orow = O + (size_t)(b * 2048 + q0 + wave * 32 + qg * 16 + l16) * 1024 + h * 64;
        #pragma unroll
        for (int dt = 0; dt < 4; ++dt) {
            unsigned short ob[4];
            #pragma unroll
            for (int r = 0; r < 4; ++r) ob[r] = f2bf(oa[qg][dt][r] * linv);
            *(uint2*)(orow + dt * 16 + quad * 4) = *(const uint2*)ob;
        }
    }
}

// ---------------------------------------------------------------------------
// Mid LayerNorm pair (grid 16384)
// ---------------------------------------------------------------------------
__global__ __launch_bounds__(256) void ln2_kernel(
    const unsigned short* __restrict__ in0, const unsigned short* __restrict__ in1,
    unsigned short* __restrict__ out,
    const float* __restrict__ w0, const float* __restrict__ b0,
    const float* __restrict__ w1, const float* __restrict__ b1)
{
    __shared__ float red[8];
    const int sel = blockIdx.x >> 13;
    const int row = blockIdx.x & 8191;
    const unsigned short* in = sel ? in1 : in0;
    const float* w = sel ? w1 : w0;
    const float* bb = sel ? b1 : b0;
    const int tid = threadIdx.x;
    const int wave = tid >> 6, lane = tid & 63;
    uint2 raw = *(const uint2*)(in + (size_t)row * 1024 + tid * 4);
    float v[4];
    v[0] = bf2f((unsigned short)(raw.x & 0xffffu));
    v[1] = bf2f((unsigned short)(raw.x >> 16));
    v[2] = bf2f((unsigned short)(raw.y & 0xffffu));
    v[3] = bf2f((unsigned short)(raw.y >> 16));
    float s = v[0] + v[1] + v[2] + v[3];
    float sq = v[0] * v[0] + v[1] * v[1] + v[2] * v[2] + v[3] * v[3];
    #pragma unroll
    for (int m = 1; m < 64; m <<= 1) { s += __shfl_xor(s, m); sq += __shfl_xor(sq, m); }
    if (lane == 0) { red[wave] = s; red[4 + wave] = sq; }
    __syncthreads();
    s = red[0] + red[1] + red[2] + red[3];
    sq = red[4] + red[5] + red[6] + red[7];
    const float mu = s * (1.0f / 1024.0f);
    const float var = sq * (1.0f / 1024.0f) - mu * mu;
    const float rstd = rsqrtf(var + 1e-5f);
    unsigned short ob[4];
    #pragma unroll
    for (int j = 0; j < 4; ++j)
        ob[j] = f2bf((v[j] - mu) * rstd * w[tid * 4 + j] + bb[tid * 4 + j]);
    *(uint2*)(out + (size_t)row * 2048 + sel * 1024 + tid * 4) = *(uint2*)ob;
}

// ---------------------------------------------------------------------------
// Final LayerNorm -> fp32 d_out (grid 8192)
// ---------------------------------------------------------------------------
__global__ __launch_bounds__(256) void ln_final_kernel(
    const unsigned short* __restrict__ in, float* __restrict__ out,
    const float* __restrict__ w, const float* __restrict__ bias)
{
    __shared__ float red[8];
    const int row = blockIdx.x;
    const int tid = threadIdx.x;
    const int wave = tid >> 6, lane = tid & 63;
    uint2 raw = *(const uint2*)(in + (size_t)row * 1024 + tid * 4);
    float v[4];
    v[0] = bf2f((unsigned short)(raw.x & 0xffffu));
    v[1] = bf2f((unsigned short)(raw.x >> 16));
    v[2] = bf2f((unsigned short)(raw.y & 0xffffu));
    v[3] = bf2f((unsigned short)(raw.y >> 16));
    float s = v[0] + v[1] + v[2] + v[3];
    float sq = v[0] * v[0] + v[1] * v[1] + v[2] * v[2] + v[3] * v[3];
    #pragma unroll
    for (int m = 1; m < 64; m <<= 1) { s += __shfl_xor(s, m); sq += __shfl_xor(sq, m); }
    if (lane == 0) { red[wave] = s; red[4 + wave] = sq; }
    __syncthreads();
    s = red[0] + red[1] + red[2] + red[3];
    sq = red[4] + red[5] + red[6] + red[7];
    const float mu = s * (1.0f / 1024.0f);
    const float var = sq * (1.0f / 1024.0f) - mu * mu;
    const float rstd = rsqrtf(var + 1e-5f);
    float o[4];
    #pragma unroll
    for (int j = 0; j < 4; ++j)
        o[j] = (v[j] - mu) * rstd * w[tid * 4 + j] + bias[tid * 4 + j];
    *(float4*)(out + (size_t)row * 1024 + tid * 4) = (float4){o[0], o[1], o[2], o[3]};
}

// ---------------------------------------------------------------------------
extern "C" void kernel_launch(void* const* d_in, const int* in_sizes, int n_in,
                              void* d_out, int out_size, void* d_ws, size_t ws_size,
                              hipStream_t stream)
{
    (void)in_sizes; (void)n_in; (void)out_size; (void)ws_size;
    const float* temporal = (const float*)d_in[0];
    const float* feature  = (const float*)d_in[1];
    const float* qt_w = (const float*)d_in[2];
    const float* qt_b = (const float*)d_in[3];
    const float* kf_w = (const float*)d_in[4];
    const float* kf_b = (const float*)d_in[5];
    const float* vf_w = (const float*)d_in[6];
    const float* vf_b = (const float*)d_in[7];
    const float* qf_w = (const float*)d_in[8];
    const float* qf_b = (const float*)d_in[9];
    const float* kt_w = (const float*)d_in[10];
    const float* kt_b = (const float*)d_in[11];
    const float* vt_w = (const float*)d_in[12];
    const float* vt_b = (const float*)d_in[13];
    const float* ot_w = (const float*)d_in[14];
    const float* ot_b = (const float*)d_in[15];
    const float* of_w = (const float*)d_in[16];
    const float* of_b = (const float*)d_in[17];
    const float* fus1_w = (const float*)d_in[18];
    const float* fus1_b = (const float*)d_in[19];
    const float* fus2_w = (const float*)d_in[20];
    const float* fus2_b = (const float*)d_in[21];
    const float* ln_fus_w = (const float*)d_in[22];
    const float* ln_fus_b = (const float*)d_in[23];
    const float* ln_t_w = (const float*)d_in[24];
    const float* ln_t_b = (const float*)d_in[25];
    const float* ln_f_w = (const float*)d_in[26];
    const float* ln_f_b = (const float*)d_in[27];

    unsigned short* p = (unsigned short*)d_ws;
    const size_t EW = 1024ull * 1024;
    const size_t ET = 8192ull * 1024;
    unsigned short* WT3t = p;
    unsigned short* WT3f = p + 3 * EW;
    unsigned short* WTot = p + 6 * EW;
    unsigned short* WTof = p + 7 * EW;
    unsigned short* WTf1 = p + 8 * EW;
    unsigned short* WTf2 = p + 10 * EW;
    size_t off = 11 * EW;
    unsigned short* Tb = p + off; off += ET;
    unsigned short* Fb = p + off; off += ET;
    unsigned short* Qt = p + off; off += ET;
    unsigned short* Kt = p + off; off += ET;
    unsigned short* Vt = p + off; off += ET;   // scratch span for comb
    unsigned short* Qf = p + off; off += ET;
    unsigned short* Kf = p + off; off += ET;
    unsigned short* Vf = p + off; off += ET;   // scratch for y2
    unsigned short* VfT = p + off; off += ET;
    unsigned short* VtT = p + off; off += ET;
    unsigned short* attnT = p + off; off += ET;
    unsigned short* attnF = p + off; off += ET;
    unsigned short* yT = Qt;
    unsigned short* yF = Qf;
    unsigned short* comb = Kt;   // spans Kt+Vt: [8192][2048]
    unsigned short* hbuf = Kf;
    unsigned short* y2 = Vf;
    (void)Vt;

    const float SC = 0.125f * 1.4426950408889634f;

    // 0+1) merged prep: weight transposes + token conversion
    {
        WX P;
        const float* srcs[10] = {qt_w, kt_w, vt_w, qf_w, kf_w, vf_w,
                                 ot_w, of_w, fus1_w, fus2_w};
        unsigned long long dsts[10] = {
            0, EW, 2 * EW,
            3 * EW, 4 * EW, 5 * EW,
            6 * EW, 7 * EW, 8 * EW, 10 * EW};
        int cum = 0;
        P.cum[0] = 0;
        for (int i = 0; i < 10; ++i) {
            P.src[i] = srcs[i];
            P.dst[i] = dsts[i];
            P.r64[i] = (i == 8) ? 32 : 16;
            cum += P.r64[i] * 16;
            P.cum[i + 1] = cum;
        }
        prep_kernel<<<cum + 2048, 256, 0, stream>>>(P, p, temporal, feature, Tb, Fb);
    }

    const dim3 gb(256);
    // 2) merged QKV projections, both streams; V written transposed directly
    gemm_qkv_kernel<<<dim3(64, 48), gb, 0, stream>>>(
        Tb, WT3t, qt_b, kt_b, vt_b, Qt, Kt, VtT,
        Fb, WT3f, qf_b, kf_b, vf_b, Qf, Kf, VfT, SC);
    // 3) merged flash, both streams, XCD-clustered flat grid
    flash_kernel<<<2048, gb, 0, stream>>>(
        Qt, Kf, VfT, attnT, Qf, Kt, VtT, attnF);
    // 4) merged output projections + residual
    gemm_out_kernel<<<dim3(64, 16), gb, 0, stream>>>(
        attnT, WTot, ot_b, temporal, yT,
        attnF, WTof, of_b, feature,  yF);
    // 5) mid LayerNorm pair -> comb
    ln2_kernel<<<16384, gb, 0, stream>>>(yT, yF, comb, ln_t_w, ln_t_b, ln_f_w, ln_f_b);
    // 6) fusion MLP
    gemm_kernel<2><<<dim3(64, 8), gb, 0, stream>>>(comb, WTf1, fus1_b, hbuf, 1024, 2048);
    gemm_kernel<0><<<dim3(64, 8), gb, 0, stream>>>(hbuf, WTf2, fus2_b, y2, 1024, 1024);
    // 7) final LN -> fp32 d_out
    ln_final_kernel<<<8192, gb, 0, stream>>>(y2, (float*)d_out, ln_fus_w, ln_fus_b);
}

// Round 4
// 660.313 us; speedup vs baseline: 1.0239x; 1.0239x over previous
//
#include <hip/hip_runtime.h>
#include <math.h>

typedef __attribute__((ext_vector_type(8))) short short8;
typedef __attribute__((ext_vector_type(4))) short short4v;
typedef __attribute__((ext_vector_type(4))) float floatx4;
typedef __attribute__((ext_vector_type(16))) float floatx16;

#define GLOBAL_AS __attribute__((address_space(1)))
#define LDS_AS __attribute__((address_space(3)))

__device__ __forceinline__ float bf2f(unsigned short u) {
    unsigned int x = ((unsigned int)u) << 16;
    return __builtin_bit_cast(float, x);
}
__device__ __forceinline__ unsigned short f2bf(float f) {
    unsigned int u = __builtin_bit_cast(unsigned int, f);
    u += 0x7fffu + ((u >> 16) & 1u);
    return (unsigned short)(u >> 16);
}

// ---------------------------------------------------------------------------
// Merged prep: weight transposes + token fp32->bf16.  (unchanged)
// ---------------------------------------------------------------------------
struct WX {
    const float* src[10];
    unsigned long long dst[10];
    int r64[10];
    int cum[11];
};

__global__ __launch_bounds__(256) void prep_kernel(
    WX P, unsigned short* __restrict__ base,
    const float* __restrict__ ta, const float* __restrict__ tb,
    unsigned short* __restrict__ oa, unsigned short* __restrict__ ob)
{
    __shared__ unsigned short T[64][72];
    const int bx = blockIdx.x;
    if (bx >= P.cum[10]) {
        const int cb = bx - P.cum[10];
        const float* in = cb < 1024 ? ta : tb;
        unsigned short* out = cb < 1024 ? oa : ob;
        const size_t b0 = (size_t)(cb & 1023) * 8192;
        #pragma unroll
        for (int j = 0; j < 8; ++j) {
            const size_t i = b0 + (size_t)j * 1024 + threadIdx.x * 4;
            float4 f = *(const float4*)(in + i);
            unsigned short o[4] = {f2bf(f.x), f2bf(f.y), f2bf(f.z), f2bf(f.w)};
            *(uint2*)(out + i) = *(const uint2*)o;
        }
        return;
    }
    int w = 0;
    #pragma unroll
    for (int i = 0; i < 10; ++i) if (bx >= P.cum[i + 1]) w = i + 1;
    const int tix = bx - P.cum[w];
    const int R = P.r64[w] * 64;
    const int r0 = (tix >> 4) * 64, c0 = (tix & 15) * 64;
    const float* in = P.src[w];
    unsigned short* out = base + P.dst[w];
    const int t = threadIdx.x;
    {
        const int r = t >> 2, cc = (t & 3) * 16;
        const float* p = in + (size_t)(r0 + r) * 1024 + c0 + cc;
        #pragma unroll
        for (int j = 0; j < 16; j += 4) {
            float4 f = *(const float4*)(p + j);
            T[cc + j + 0][r] = f2bf(f.x);
            T[cc + j + 1][r] = f2bf(f.y);
            T[cc + j + 2][r] = f2bf(f.z);
            T[cc + j + 3][r] = f2bf(f.w);
        }
    }
    __syncthreads();
    {
        const int c = t >> 2, rr = (t & 3) * 16;
        unsigned short* q = out + (size_t)(c0 + c) * R + r0 + rr;
        *(uint4*)(q)     = *(const uint4*)(&T[c][rr]);
        *(uint4*)(q + 8) = *(const uint4*)(&T[c][rr + 8]);
    }
}

// ===========================================================================
// R3: 256x256 deep-pipelined GEMM core (T3+T4+T5 on top of proven T2 swizzle).
// BK=64, 8 waves (2M x 4N), wave tile 128x64 (m16 frags: 8 M-rep x 4 N-rep),
// 16x16x32 MFMA operand-swapped (D row m = lane&15, col n = quad*4+reg).
// Wave M/N sub-tiles remapped so each phase's ds_reads free a CONTIGUOUS
// 128-row half-tile:
//   m_local(mi) = (mi>>2)*128 + wr*64 + (mi&3)*16 + l16   (mi0-3 = A-half0)
//   n_local(j)  = (j>>1)*128  + wc*32 + (j&1)*16 + quad*4 (j0-1  = B-half0)
// LDS: 2 buffers x (A 32KB + B 32KB) = 128 KiB. Per K-tile 4 phases:
//   p1: read af(mh0)+bf(nh0)                      ; MFMA mh0 x n0-1
//   p2: read bf(nh1); stage A0,B0(t+2)->freed     ; MFMA mh0 x n2-3
//   p3: read af(mh1); stage B1(t+2)               ; MFMA mh1 x n2-3
//   p4: stage A1(t+2); s_waitcnt vmcnt(8) (t+1 landed, t+2 in flight); MFMA
// Each phase: lgkmcnt(0)+sched_barrier+s_barrier BEFORE its MFMA cluster so
// the barrier genuinely frees the region the next phase stages into.
// Counted vmcnt(8) is the ONLY vm wait in steady state (T4: never drain 0).
// setprio(1) around each 16-MFMA cluster (T5 -- gated on phase split).
// Stage: global_load_lds w=16, lane-linear dest, pre-swizzled source col
// (both-sides swizzle, rule 21); read slot = ((kk*4+quad) ^ (r&7))*8.
// ===========================================================================
#define G256_DECL(A_, B_, Kdim)                                               \
    const int tid = threadIdx.x;                                              \
    const int wave = tid >> 6, lane = tid & 63;                               \
    const int quad = lane >> 4, l16 = lane & 15;                              \
    const int wr = wave >> 2, wc = wave & 3;                                  \
    const int lrow8 = lane >> 3, lc8 = lane & 7;                              \
    floatx4 acc[8][4];                                                        \
    _Pragma("unroll")                                                         \
    for (int i = 0; i < 8; ++i)                                               \
        _Pragma("unroll")                                                     \
        for (int j = 0; j < 4; ++j) acc[i][j] = (floatx4){0.f, 0.f, 0.f, 0.f}; \
    const unsigned short* sA[4];                                              \
    const unsigned short* sB[4];                                              \
    int ldst[4];                                                              \
    _Pragma("unroll")                                                         \
    for (int h = 0; h < 2; ++h)                                               \
        _Pragma("unroll")                                                     \
        for (int j = 0; j < 2; ++j) {                                         \
            const int r0 = h * 128 + j * 64 + wave * 8;                       \
            const int r = r0 + lrow8;                                         \
            const int cg = lc8 ^ (r & 7);                                     \
            sA[h * 2 + j] = (A_) + (size_t)(bm + r) * (Kdim) + cg * 8;        \
            sB[h * 2 + j] = (B_) + (size_t)(bn + r) * (Kdim) + cg * 8;        \
            ldst[h * 2 + j] = r0 * 64;                                        \
        }

#define G256_STG_A(s_) __builtin_amdgcn_global_load_lds(                      \
    (const GLOBAL_AS void*)(sA[s_] + ko), (LDS_AS void*)(L + cb + ldst[s_]), 16, 0, 0)
#define G256_STG_B(s_) __builtin_amdgcn_global_load_lds(                      \
    (const GLOBAL_AS void*)(sB[s_] + ko), (LDS_AS void*)(L + cb + 16384 + ldst[s_]), 16, 0, 0)

#define G256_LDA(mh_)                                                         \
    _Pragma("unroll")                                                         \
    for (int mi = 0; mi < 4; ++mi) {                                          \
        const int r = (mh_) * 128 + wr * 64 + mi * 16 + l16;                  \
        _Pragma("unroll")                                                     \
        for (int kk = 0; kk < 2; ++kk)                                        \
            afc[mi][kk] = *(const short8*)&L[cb + r * 64 +                    \
                (((kk * 4 + quad) ^ (r & 7)) * 8)];                           \
    }
#define G256_LDB(nh_)                                                         \
    _Pragma("unroll")                                                         \
    for (int nj = 0; nj < 2; ++nj) {                                          \
        const int r = (nh_) * 128 + wc * 32 + nj * 16 + l16;                  \
        _Pragma("unroll")                                                     \
        for (int kk = 0; kk < 2; ++kk)                                        \
            bfr[(nh_) * 2 + nj][kk] = *(const short8*)&L[cb + 16384 + r * 64 +\
                (((kk * 4 + quad) ^ (r & 7)) * 8)];                           \
    }

#define G256_FENCE() do {                                                     \
    asm volatile("s_waitcnt lgkmcnt(0)" ::: "memory");                        \
    __builtin_amdgcn_sched_barrier(0);                                        \
    __builtin_amdgcn_s_barrier(); } while (0)

#define G256_MM(mh_, nb_) do {                                                \
    __builtin_amdgcn_s_setprio(1);                                            \
    _Pragma("unroll")                                                         \
    for (int mi = 0; mi < 4; ++mi)                                            \
        _Pragma("unroll")                                                     \
        for (int nj = 0; nj < 2; ++nj)                                        \
            _Pragma("unroll")                                                 \
            for (int kk = 0; kk < 2; ++kk)                                    \
                acc[(mh_) * 4 + mi][(nb_) + nj] =                             \
                    __builtin_amdgcn_mfma_f32_16x16x32_bf16(                  \
                        bfr[(nb_) + nj][kk], afc[mi][kk],                     \
                        acc[(mh_) * 4 + mi][(nb_) + nj], 0, 0, 0);            \
    __builtin_amdgcn_s_setprio(0); } while (0)

#define G256_CORE(A_, B_, Kdim)                                               \
    G256_DECL(A_, B_, Kdim)                                                   \
    {   /* prologue: stage tile0 -> buf0, tile1 -> buf1 */                    \
        _Pragma("unroll")                                                     \
        for (int s = 0; s < 4; ++s) {                                         \
            __builtin_amdgcn_global_load_lds((const GLOBAL_AS void*)(sA[s]),  \
                (LDS_AS void*)(L + ldst[s]), 16, 0, 0);                       \
            __builtin_amdgcn_global_load_lds((const GLOBAL_AS void*)(sB[s]),  \
                (LDS_AS void*)(L + 16384 + ldst[s]), 16, 0, 0);               \
        }                                                                     \
        _Pragma("unroll")                                                     \
        for (int s = 0; s < 4; ++s) {                                         \
            __builtin_amdgcn_global_load_lds((const GLOBAL_AS void*)(sA[s] + 64), \
                (LDS_AS void*)(L + 32768 + ldst[s]), 16, 0, 0);               \
            __builtin_amdgcn_global_load_lds((const GLOBAL_AS void*)(sB[s] + 64), \
                (LDS_AS void*)(L + 32768 + 16384 + ldst[s]), 16, 0, 0);       \
        }                                                                     \
        asm volatile("s_waitcnt vmcnt(8)" ::: "memory");                      \
        __builtin_amdgcn_s_barrier();                                         \
    }                                                                         \
    short8 afc[4][2];                                                         \
    short8 bfr[4][2];                                                         \
    const int NT = (Kdim) >> 6;                                               \
    for (int t = 0; t < NT; ++t) {                                            \
        const int cb = (t & 1) << 15;                                         \
        const int ko = (t + 2) << 6;                                          \
        const bool stg = (t < NT - 2);                                        \
        /* p1 */                                                              \
        G256_LDA(0)                                                           \
        G256_LDB(0)                                                           \
        G256_FENCE();                                                         \
        G256_MM(0, 0);                                                        \
        /* p2 */                                                              \
        G256_LDB(1)                                                           \
        if (stg) { G256_STG_A(0); G256_STG_A(1); G256_STG_B(0); G256_STG_B(1); } \
        G256_FENCE();                                                         \
        G256_MM(0, 2);                                                        \
        /* p3 */                                                              \
        G256_LDA(1)                                                           \
        if (stg) { G256_STG_B(2); G256_STG_B(3); }                            \
        G256_FENCE();                                                         \
        G256_MM(1, 2);                                                        \
        /* p4 */                                                              \
        if (stg) {                                                            \
            G256_STG_A(2); G256_STG_A(3);                                     \
            asm volatile("s_waitcnt vmcnt(8)" ::: "memory");                  \
        } else {                                                              \
            asm volatile("s_waitcnt vmcnt(0)" ::: "memory");                  \
        }                                                                     \
        __builtin_amdgcn_sched_barrier(0);                                    \
        __builtin_amdgcn_s_barrier();                                         \
        G256_MM(1, 0);                                                        \
    }

// Epilogue index helpers (per frag i=0..7, j=0..3):
//   m_local = (i>>2)*128 + wr*64 + (i&3)*16 + l16
//   n_local = (j>>1)*128 + wc*32 + (j&1)*16 + quad*4  (+r, r=0..3)

// ---------------------------------------------------------------------------
// Generic 256^2 GEMM: MODE 0 plain, MODE 2 exact GELU. grid (M/256, N/256).
// ---------------------------------------------------------------------------
template <int MODE>
__global__ __launch_bounds__(512, 2) void gemm_kernel(
    const unsigned short* __restrict__ A,
    const unsigned short* __restrict__ Wt,
    const float* __restrict__ bias,
    unsigned short* __restrict__ C,
    int N, int K)
{
    __shared__ unsigned short L[65536];
    const int bm = blockIdx.x * 256, bn = blockIdx.y * 256;
    G256_CORE(A, Wt, K)

    #pragma unroll
    for (int i = 0; i < 8; ++i) {
        const int m = bm + (i >> 2) * 128 + wr * 64 + (i & 3) * 16 + l16;
        #pragma unroll
        for (int j = 0; j < 4; ++j) {
            const int n0 = bn + (j >> 1) * 128 + wc * 32 + (j & 1) * 16 + quad * 4;
            float4 bv = *(const float4*)&bias[n0];
            float v[4];
            #pragma unroll
            for (int r = 0; r < 4; ++r)
                v[r] = acc[i][j][r] + ((const float*)&bv)[r];
            if (MODE == 2) {
                #pragma unroll
                for (int r = 0; r < 4; ++r)
                    v[r] = 0.5f * v[r] * (1.0f + erff(v[r] * 0.70710678118f));
            }
            unsigned short o[4] = {f2bf(v[0]), f2bf(v[1]), f2bf(v[2]), f2bf(v[3])};
            *(uint2*)&C[(size_t)m * N + n0] = *(const uint2*)o;
        }
    }
}

// ---------------------------------------------------------------------------
// Merged output-projection GEMM, both streams + residual. grid (32, 8).
// ---------------------------------------------------------------------------
__global__ __launch_bounds__(512, 2) void gemm_out_kernel(
    const unsigned short* __restrict__ A0, const unsigned short* __restrict__ W0,
    const float* __restrict__ bi0, const float* __restrict__ r0, unsigned short* __restrict__ C0,
    const unsigned short* __restrict__ A1, const unsigned short* __restrict__ W1,
    const float* __restrict__ bi1, const float* __restrict__ r1, unsigned short* __restrict__ C1)
{
    __shared__ unsigned short L[65536];
    const int s1 = blockIdx.y >> 2;
    const unsigned short* A = s1 ? A1 : A0;
    const unsigned short* Wt = s1 ? W1 : W0;
    const float* bias = s1 ? bi1 : bi0;
    const float* resid = s1 ? r1 : r0;
    unsigned short* C = s1 ? C1 : C0;
    const int bm = blockIdx.x * 256, bn = (blockIdx.y & 3) * 256;
    G256_CORE(A, Wt, 1024)

    #pragma unroll
    for (int i = 0; i < 8; ++i) {
        const int m = bm + (i >> 2) * 128 + wr * 64 + (i & 3) * 16 + l16;
        #pragma unroll
        for (int j = 0; j < 4; ++j) {
            const int n0 = bn + (j >> 1) * 128 + wc * 32 + (j & 1) * 16 + quad * 4;
            float4 bv = *(const float4*)&bias[n0];
            float4 rv = *(const float4*)&resid[(size_t)m * 1024 + n0];
            float v[4];
            v[0] = acc[i][j][0] + bv.x + rv.x;
            v[1] = acc[i][j][1] + bv.y + rv.y;
            v[2] = acc[i][j][2] + bv.z + rv.z;
            v[3] = acc[i][j][3] + bv.w + rv.w;
            unsigned short o[4] = {f2bf(v[0]), f2bf(v[1]), f2bf(v[2]), f2bf(v[3])};
            *(uint2*)&C[(size_t)m * 1024 + n0] = *(const uint2*)o;
        }
    }
}

// ---------------------------------------------------------------------------
// Merged QKV GEMM, both streams. grid (32, 24). buf 0 (Q): pre-scaled.
// buf 2 (V): per-head transposed layout with d&8 half-swap.
// ---------------------------------------------------------------------------
__global__ __launch_bounds__(512, 2) void gemm_qkv_kernel(
    const unsigned short* __restrict__ At, const unsigned short* __restrict__ Wt3t,
    const float* __restrict__ tb0, const float* __restrict__ tb1, const float* __restrict__ tb2,
    unsigned short* __restrict__ to0, unsigned short* __restrict__ to1, unsigned short* __restrict__ to2,
    const unsigned short* __restrict__ Af, const unsigned short* __restrict__ Wt3f,
    const float* __restrict__ fb0, const float* __restrict__ fb1, const float* __restrict__ fb2,
    unsigned short* __restrict__ fo0, unsigned short* __restrict__ fo1, unsigned short* __restrict__ fo2,
    float scale0)
{
    __shared__ unsigned short L[65536];
    const int str = blockIdx.y >= 12;
    const unsigned short* A = str ? Af : At;
    const unsigned short* Wt = str ? Wt3f : Wt3t;
    const int byy = str ? (blockIdx.y - 12) : blockIdx.y;
    const int buf = byy >> 2;
    const int bn = byy * 256;
    const int cn = (byy & 3) * 256;
    const float* bias = str ? (buf == 0 ? fb0 : (buf == 1 ? fb1 : fb2))
                            : (buf == 0 ? tb0 : (buf == 1 ? tb1 : tb2));
    unsigned short* C = str ? (buf == 0 ? fo0 : (buf == 1 ? fo1 : fo2))
                            : (buf == 0 ? to0 : (buf == 1 ? to1 : to2));
    const float scale = buf == 0 ? scale0 : 1.0f;
    const int bm = blockIdx.x * 256;
    G256_CORE(A, Wt, 1024)

    #pragma unroll
    for (int i = 0; i < 8; ++i) {
        const int m = bm + (i >> 2) * 128 + wr * 64 + (i & 3) * 16 + l16;
        #pragma unroll
        for (int j = 0; j < 4; ++j) {
            const int n0 = cn + (j >> 1) * 128 + wc * 32 + (j & 1) * 16 + quad * 4;
            float4 bv = *(const float4*)&bias[n0];
            unsigned short o[4];
            #pragma unroll
            for (int r = 0; r < 4; ++r)
                o[r] = f2bf((acc[i][j][r] + ((const float*)&bv)[r]) * scale);
            if (buf == 2) {
                const int b = m >> 11, tk = m & 2047;
                const int h = n0 >> 6, d0 = n0 & 63;
                const int tsw = tk ^ ((d0 & 8) ? 4 : 0);
                unsigned short* vb = C + ((size_t)(b * 16 + h) * 64) * 2048 + tsw;
                #pragma unroll
                for (int r = 0; r < 4; ++r) vb[(size_t)(d0 + r) * 2048] = o[r];
            } else {
                *(uint2*)&C[(size_t)m * 1024 + n0] = *(const uint2*)o;
            }
        }
    }
}

// ---------------------------------------------------------------------------
// Merged flash, flat grid 2048, XCD-clustered. (unchanged from R1: 16KB LDS
// single-buffer high-occupancy config + v_cvt_pk_bf16_f32 P-packing.)
// ---------------------------------------------------------------------------
__global__ __launch_bounds__(256) void flash_kernel(
    const unsigned short* __restrict__ Q0, const unsigned short* __restrict__ K0,
    const unsigned short* __restrict__ V0, unsigned short* __restrict__ O0,
    const unsigned short* __restrict__ Q1, const unsigned short* __restrict__ K1,
    const unsigned short* __restrict__ V1, unsigned short* __restrict__ O1)
{
    __shared__ unsigned short Ks[64 * 64];
    __shared__ unsigned short Vs[64 * 64];

    const int bid = blockIdx.x;
    const int p = (bid & 7) * 16 + (bid >> 7);
    const int qt = (bid >> 3) & 15;
    const int s1 = p >= 64;
    const int rem = p & 63;
    const int b = rem >> 4, h = rem & 15;
    const unsigned short* Q = s1 ? Q1 : Q0;
    const unsigned short* Kmat = s1 ? K1 : K0;
    const unsigned short* Vtp = s1 ? V1 : V0;
    unsigned short* O = s1 ? O1 : O0;
    const int q0 = qt * 128;

    const int tid = threadIdx.x;
    const int wave = tid >> 6, lane = tid & 63;
    const int quad = lane >> 4, l16 = lane & 15;

    const unsigned short* qp = Q + (size_t)(b * 2048 + q0 + wave * 32 + l16) * 1024 + h * 64;
    short8 qf[2][2];
    qf[0][0] = *(const short8*)(qp + quad * 8);
    qf[0][1] = *(const short8*)(qp + 32 + quad * 8);
    qf[1][0] = *(const short8*)(qp + 16 * 1024 + quad * 8);
    qf[1][1] = *(const short8*)(qp + 16 * 1024 + 32 + quad * 8);

    const int srow8 = lane >> 3;
    const int c8 = lane & 7;
    const int rit0 = wave * 16 + srow8;
    const int rit1 = rit0 + 8;
    const int col0 = (c8 ^ (rit0 & 7)) * 8;
    const int col1 = (c8 ^ (rit1 & 7)) * 8;
    const unsigned short* kbase = Kmat + (size_t)b * 2048 * 1024 + h * 64;
    const unsigned short* vbase = Vtp + (size_t)(b * 16 + h) * 64 * 2048;
    unsigned short* lk0 = Ks + (wave * 16) * 64;
    unsigned short* lk1 = lk0 + 8 * 64;
    unsigned short* lv0 = Vs + (wave * 16) * 64;
    unsigned short* lv1 = lv0 + 8 * 64;

    int koff[4][2];
    #pragma unroll
    for (int nt = 0; nt < 4; ++nt)
        #pragma unroll
        for (int hh = 0; hh < 2; ++hh)
            koff[nt][hh] = (nt * 16 + l16) * 64 + (((hh * 4 + quad) ^ (l16 & 7)) * 8);
    int voff[4][4];
    #pragma unroll
    for (int dt = 0; dt < 4; ++dt)
        #pragma unroll
        for (int nt = 0; nt < 4; ++nt)
            voff[dt][nt] = (dt * 16 + l16) * 64 +
                           (((nt * 2 + (quad >> 1)) ^ (l16 & 7)) * 8) +
                           (((quad & 1) ^ (l16 >> 3)) * 4);

    floatx4 oa[2][4], la[2];
    #pragma unroll
    for (int qg = 0; qg < 2; ++qg) {
        la[qg] = (floatx4){0.f, 0.f, 0.f, 0.f};
        #pragma unroll
        for (int dt = 0; dt < 4; ++dt) oa[qg][dt] = (floatx4){0.f, 0.f, 0.f, 0.f};
    }
    const short4v vone = {(short)0x3F80, (short)0x3F80, (short)0x3F80, (short)0x3F80};

    for (int kt = 0; kt < 32; ++kt) {
        const unsigned short* kg0 = kbase + (size_t)(kt * 64 + rit0) * 1024 + col0;
        const unsigned short* kg1 = kbase + (size_t)(kt * 64 + rit1) * 1024 + col1;
        const unsigned short* vg0 = vbase + (size_t)rit0 * 2048 + kt * 64 + col0;
        const unsigned short* vg1 = vbase + (size_t)rit1 * 2048 + kt * 64 + col1;
        __builtin_amdgcn_global_load_lds((const GLOBAL_AS void*)kg0, (LDS_AS void*)lk0, 16, 0, 0);
        __builtin_amdgcn_global_load_lds((const GLOBAL_AS void*)kg1, (LDS_AS void*)lk1, 16, 0, 0);
        __builtin_amdgcn_global_load_lds((const GLOBAL_AS void*)vg0, (LDS_AS void*)lv0, 16, 0, 0);
        __builtin_amdgcn_global_load_lds((const GLOBAL_AS void*)vg1, (LDS_AS void*)lv1, 16, 0, 0);
        __syncthreads();

        short4v pf[2][4];
        #pragma unroll
        for (int nt = 0; nt < 4; ++nt) {
            short8 k0 = *(const short8*)&Ks[koff[nt][0]];
            short8 k1 = *(const short8*)&Ks[koff[nt][1]];
            #pragma unroll
            for (int qg = 0; qg < 2; ++qg) {
                floatx4 s = (floatx4){0.f, 0.f, 0.f, 0.f};
                s = __builtin_amdgcn_mfma_f32_16x16x32_bf16(k0, qf[qg][0], s, 0, 0, 0);
                s = __builtin_amdgcn_mfma_f32_16x16x32_bf16(k1, qf[qg][1], s, 0, 0, 0);
                float p0 = __builtin_amdgcn_exp2f(s[0]);
                float p1 = __builtin_amdgcn_exp2f(s[1]);
                float p2 = __builtin_amdgcn_exp2f(s[2]);
                float p3 = __builtin_amdgcn_exp2f(s[3]);
                union { unsigned u[2]; short4v s4; } pk;
                asm("v_cvt_pk_bf16_f32 %0, %1, %2"
                    : "=v"(pk.u[0]) : "v"(p0), "v"(p1));
                asm("v_cvt_pk_bf16_f32 %0, %1, %2"
                    : "=v"(pk.u[1]) : "v"(p2), "v"(p3));
                pf[qg][nt] = pk.s4;
                la[qg] = __builtin_amdgcn_mfma_f32_16x16x16bf16_1k(vone, pf[qg][nt], la[qg], 0, 0, 0);
            }
        }
        #pragma unroll
        for (int dt = 0; dt < 4; ++dt)
            #pragma unroll
            for (int nt = 0; nt < 4; ++nt) {
                short4v vf = *(const short4v*)&Vs[voff[dt][nt]];
                oa[0][dt] = __builtin_amdgcn_mfma_f32_16x16x16bf16_1k(vf, pf[0][nt], oa[0][dt], 0, 0, 0);
                oa[1][dt] = __builtin_amdgcn_mfma_f32_16x16x16bf16_1k(vf, pf[1][nt], oa[1][dt], 0, 0, 0);
            }
        __syncthreads();
    }

    #pragma unroll
    for (int qg = 0; qg < 2; ++qg) {
        const float linv = 1.0f / la[qg][0];
        unsigned short* orow = O + (size_t)(b * 2048 + q0 + wave * 32 + qg * 16 + l16) * 1024 + h * 64;
        #pragma unroll
        for (int dt = 0; dt < 4; ++dt) {
            unsigned short ob[4];
            #pragma unroll
            for (int r = 0; r < 4; ++r) ob[r] = f2bf(oa[qg][dt][r] * linv);
            *(uint2*)(orow + dt * 16 + quad * 4) = *(const uint2*)ob;
        }
    }
}

// ---------------------------------------------------------------------------
// Mid LayerNorm pair (grid 16384)
// ---------------------------------------------------------------------------
__global__ __launch_bounds__(256) void ln2_kernel(
    const unsigned short* __restrict__ in0, const unsigned short* __restrict__ in1,
    unsigned short* __restrict__ out,
    const float* __restrict__ w0, const float* __restrict__ b0,
    const float* __restrict__ w1, const float* __restrict__ b1)
{
    __shared__ float red[8];
    const int sel = blockIdx.x >> 13;
    const int row = blockIdx.x & 8191;
    const unsigned short* in = sel ? in1 : in0;
    const float* w = sel ? w1 : w0;
    const float* bb = sel ? b1 : b0;
    const int tid = threadIdx.x;
    const int wave = tid >> 6, lane = tid & 63;
    uint2 raw = *(const uint2*)(in + (size_t)row * 1024 + tid * 4);
    float v[4];
    v[0] = bf2f((unsigned short)(raw.x & 0xffffu));
    v[1] = bf2f((unsigned short)(raw.x >> 16));
    v[2] = bf2f((unsigned short)(raw.y & 0xffffu));
    v[3] = bf2f((unsigned short)(raw.y >> 16));
    float s = v[0] + v[1] + v[2] + v[3];
    float sq = v[0] * v[0] + v[1] * v[1] + v[2] * v[2] + v[3] * v[3];
    #pragma unroll
    for (int m = 1; m < 64; m <<= 1) { s += __shfl_xor(s, m); sq += __shfl_xor(sq, m); }
    if (lane == 0) { red[wave] = s; red[4 + wave] = sq; }
    __syncthreads();
    s = red[0] + red[1] + red[2] + red[3];
    sq = red[4] + red[5] + red[6] + red[7];
    const float mu = s * (1.0f / 1024.0f);
    const float var = sq * (1.0f / 1024.0f) - mu * mu;
    const float rstd = rsqrtf(var + 1e-5f);
    unsigned short ob[4];
    #pragma unroll
    for (int j = 0; j < 4; ++j)
        ob[j] = f2bf((v[j] - mu) * rstd * w[tid * 4 + j] + bb[tid * 4 + j]);
    *(uint2*)(out + (size_t)row * 2048 + sel * 1024 + tid * 4) = *(uint2*)ob;
}

// ---------------------------------------------------------------------------
// Final LayerNorm -> fp32 d_out (grid 8192)
// ---------------------------------------------------------------------------
__global__ __launch_bounds__(256) void ln_final_kernel(
    const unsigned short* __restrict__ in, float* __restrict__ out,
    const float* __restrict__ w, const float* __restrict__ bias)
{
    __shared__ float red[8];
    const int row = blockIdx.x;
    const int tid = threadIdx.x;
    const int wave = tid >> 6, lane = tid & 63;
    uint2 raw = *(const uint2*)(in + (size_t)row * 1024 + tid * 4);
    float v[4];
    v[0] = bf2f((unsigned short)(raw.x & 0xffffu));
    v[1] = bf2f((unsigned short)(raw.x >> 16));
    v[2] = bf2f((unsigned short)(raw.y & 0xffffu));
    v[3] = bf2f((unsigned short)(raw.y >> 16));
    float s = v[0] + v[1] + v[2] + v[3];
    float sq = v[0] * v[0] + v[1] * v[1] + v[2] * v[2] + v[3] * v[3];
    #pragma unroll
    for (int m = 1; m < 64; m <<= 1) { s += __shfl_xor(s, m); sq += __shfl_xor(sq, m); }
    if (lane == 0) { red[wave] = s; red[4 + wave] = sq; }
    __syncthreads();
    s = red[0] + red[1] + red[2] + red[3];
    sq = red[4] + red[5] + red[6] + red[7];
    const float mu = s * (1.0f / 1024.0f);
    const float var = sq * (1.0f / 1024.0f) - mu * mu;
    const float rstd = rsqrtf(var + 1e-5f);
    float o[4];
    #pragma unroll
    for (int j = 0; j < 4; ++j)
        o[j] = (v[j] - mu) * rstd * w[tid * 4 + j] + bias[tid * 4 + j];
    *(float4*)(out + (size_t)row * 1024 + tid * 4) = (float4){o[0], o[1], o[2], o[3]};
}

// ---------------------------------------------------------------------------
extern "C" void kernel_launch(void* const* d_in, const int* in_sizes, int n_in,
                              void* d_out, int out_size, void* d_ws, size_t ws_size,
                              hipStream_t stream)
{
    (void)in_sizes; (void)n_in; (void)out_size; (void)ws_size;
    const float* temporal = (const float*)d_in[0];
    const float* feature  = (const float*)d_in[1];
    const float* qt_w = (const float*)d_in[2];
    const float* qt_b = (const float*)d_in[3];
    const float* kf_w = (const float*)d_in[4];
    const float* kf_b = (const float*)d_in[5];
    const float* vf_w = (const float*)d_in[6];
    const float* vf_b = (const float*)d_in[7];
    const float* qf_w = (const float*)d_in[8];
    const float* qf_b = (const float*)d_in[9];
    const float* kt_w = (const float*)d_in[10];
    const float* kt_b = (const float*)d_in[11];
    const float* vt_w = (const float*)d_in[12];
    const float* vt_b = (const float*)d_in[13];
    const float* ot_w = (const float*)d_in[14];
    const float* ot_b = (const float*)d_in[15];
    const float* of_w = (const float*)d_in[16];
    const float* of_b = (const float*)d_in[17];
    const float* fus1_w = (const float*)d_in[18];
    const float* fus1_b = (const float*)d_in[19];
    const float* fus2_w = (const float*)d_in[20];
    const float* fus2_b = (const float*)d_in[21];
    const float* ln_fus_w = (const float*)d_in[22];
    const float* ln_fus_b = (const float*)d_in[23];
    const float* ln_t_w = (const float*)d_in[24];
    const float* ln_t_b = (const float*)d_in[25];
    const float* ln_f_w = (const float*)d_in[26];
    const float* ln_f_b = (const float*)d_in[27];

    unsigned short* p = (unsigned short*)d_ws;
    const size_t EW = 1024ull * 1024;
    const size_t ET = 8192ull * 1024;
    unsigned short* WT3t = p;
    unsigned short* WT3f = p + 3 * EW;
    unsigned short* WTot = p + 6 * EW;
    unsigned short* WTof = p + 7 * EW;
    unsigned short* WTf1 = p + 8 * EW;
    unsigned short* WTf2 = p + 10 * EW;
    size_t off = 11 * EW;
    unsigned short* Tb = p + off; off += ET;
    unsigned short* Fb = p + off; off += ET;
    unsigned short* Qt = p + off; off += ET;
    unsigned short* Kt = p + off; off += ET;
    unsigned short* Vt = p + off; off += ET;   // scratch span for comb
    unsigned short* Qf = p + off; off += ET;
    unsigned short* Kf = p + off; off += ET;
    unsigned short* Vf = p + off; off += ET;   // scratch for y2
    unsigned short* VfT = p + off; off += ET;
    unsigned short* VtT = p + off; off += ET;
    unsigned short* attnT = p + off; off += ET;
    unsigned short* attnF = p + off; off += ET;
    unsigned short* yT = Qt;
    unsigned short* yF = Qf;
    unsigned short* comb = Kt;   // spans Kt+Vt: [8192][2048]
    unsigned short* hbuf = Kf;
    unsigned short* y2 = Vf;
    (void)Vt;

    const float SC = 0.125f * 1.4426950408889634f;

    // 0+1) merged prep: weight transposes + token conversion
    {
        WX P;
        const float* srcs[10] = {qt_w, kt_w, vt_w, qf_w, kf_w, vf_w,
                                 ot_w, of_w, fus1_w, fus2_w};
        unsigned long long dsts[10] = {
            0, EW, 2 * EW,
            3 * EW, 4 * EW, 5 * EW,
            6 * EW, 7 * EW, 8 * EW, 10 * EW};
        int cum = 0;
        P.cum[0] = 0;
        for (int i = 0; i < 10; ++i) {
            P.src[i] = srcs[i];
            P.dst[i] = dsts[i];
            P.r64[i] = (i == 8) ? 32 : 16;
            cum += P.r64[i] * 16;
            P.cum[i + 1] = cum;
        }
        prep_kernel<<<cum + 2048, 256, 0, stream>>>(P, p, temporal, feature, Tb, Fb);
    }

    const dim3 gb5(512);
    // 2) merged QKV projections, both streams; V written transposed directly
    gemm_qkv_kernel<<<dim3(32, 24), gb5, 0, stream>>>(
        Tb, WT3t, qt_b, kt_b, vt_b, Qt, Kt, VtT,
        Fb, WT3f, qf_b, kf_b, vf_b, Qf, Kf, VfT, SC);
    // 3) merged flash, both streams, XCD-clustered flat grid
    flash_kernel<<<2048, dim3(256), 0, stream>>>(
        Qt, Kf, VfT, attnT, Qf, Kt, VtT, attnF);
    // 4) merged output projections + residual
    gemm_out_kernel<<<dim3(32, 8), gb5, 0, stream>>>(
        attnT, WTot, ot_b, temporal, yT,
        attnF, WTof, of_b, feature,  yF);
    // 5) mid LayerNorm pair -> comb
    ln2_kernel<<<16384, dim3(256), 0, stream>>>(yT, yF, comb, ln_t_w, ln_t_b, ln_f_w, ln_f_b);
    // 6) fusion MLP
    gemm_kernel<2><<<dim3(32, 4), gb5, 0, stream>>>(comb, WTf1, fus1_b, hbuf, 1024, 2048);
    gemm_kernel<0><<<dim3(32, 4), gb5, 0, stream>>>(hbuf, WTf2, fus2_b, y2, 1024, 1024);
    // 7) final LN -> fp32 d_out
    ln_final_kernel<<<8192, dim3(256), 0, stream>>>(y2, (float*)d_out, ln_fus_w, ln_fus_b);
}

// Round 5
// 621.240 us; speedup vs baseline: 1.0883x; 1.0629x over previous
//
#include <hip/hip_runtime.h>
#include <math.h>

typedef __attribute__((ext_vector_type(8))) short short8;
typedef __attribute__((ext_vector_type(4))) short short4v;
typedef __attribute__((ext_vector_type(4))) float floatx4;
typedef __attribute__((ext_vector_type(16))) float floatx16;

#define GLOBAL_AS __attribute__((address_space(1)))
#define LDS_AS __attribute__((address_space(3)))

__device__ __forceinline__ float bf2f(unsigned short u) {
    unsigned int x = ((unsigned int)u) << 16;
    return __builtin_bit_cast(float, x);
}
__device__ __forceinline__ unsigned short f2bf(float f) {
    unsigned int u = __builtin_bit_cast(unsigned int, f);
    u += 0x7fffu + ((u >> 16) & 1u);
    return (unsigned short)(u >> 16);
}

// ---------------------------------------------------------------------------
// Merged prep: weight transposes + token fp32->bf16.  (unchanged)
// ---------------------------------------------------------------------------
struct WX {
    const float* src[10];
    unsigned long long dst[10];
    int r64[10];
    int cum[11];
};

__global__ __launch_bounds__(256) void prep_kernel(
    WX P, unsigned short* __restrict__ base,
    const float* __restrict__ ta, const float* __restrict__ tb,
    unsigned short* __restrict__ oa, unsigned short* __restrict__ ob)
{
    __shared__ unsigned short T[64][72];
    const int bx = blockIdx.x;
    if (bx >= P.cum[10]) {
        const int cb = bx - P.cum[10];
        const float* in = cb < 1024 ? ta : tb;
        unsigned short* out = cb < 1024 ? oa : ob;
        const size_t b0 = (size_t)(cb & 1023) * 8192;
        #pragma unroll
        for (int j = 0; j < 8; ++j) {
            const size_t i = b0 + (size_t)j * 1024 + threadIdx.x * 4;
            float4 f = *(const float4*)(in + i);
            unsigned short o[4] = {f2bf(f.x), f2bf(f.y), f2bf(f.z), f2bf(f.w)};
            *(uint2*)(out + i) = *(const uint2*)o;
        }
        return;
    }
    int w = 0;
    #pragma unroll
    for (int i = 0; i < 10; ++i) if (bx >= P.cum[i + 1]) w = i + 1;
    const int tix = bx - P.cum[w];
    const int R = P.r64[w] * 64;
    const int r0 = (tix >> 4) * 64, c0 = (tix & 15) * 64;
    const float* in = P.src[w];
    unsigned short* out = base + P.dst[w];
    const int t = threadIdx.x;
    {
        const int r = t >> 2, cc = (t & 3) * 16;
        const float* p = in + (size_t)(r0 + r) * 1024 + c0 + cc;
        #pragma unroll
        for (int j = 0; j < 16; j += 4) {
            float4 f = *(const float4*)(p + j);
            T[cc + j + 0][r] = f2bf(f.x);
            T[cc + j + 1][r] = f2bf(f.y);
            T[cc + j + 2][r] = f2bf(f.z);
            T[cc + j + 3][r] = f2bf(f.w);
        }
    }
    __syncthreads();
    {
        const int c = t >> 2, rr = (t & 3) * 16;
        unsigned short* q = out + (size_t)(c0 + c) * R + r0 + rr;
        *(uint4*)(q)     = *(const uint4*)(&T[c][rr]);
        *(uint4*)(q + 8) = *(const uint4*)(&T[c][rr + 8]);
    }
}

// ===========================================================================
// 128x128 GEMM core (proven R0 structure): BK=64, 32x32x16 MFMA, 4 waves.
// Used for fus1/fus2 where 256^2 tiles under-fill the grid (128 blocks on
// 256 CUs -- R4 lesson).
// ===========================================================================
#define GEMM_CORE(A_, B_, Kdim)                                               \
    const int tid = threadIdx.x;                                              \
    const int wave = tid >> 6, lane = tid & 63;                               \
    const int l32 = lane & 31, hi = lane >> 5;                                \
    const int wm = (wave & 1) * 64, wn = (wave >> 1) * 64;                    \
    const int srow8 = lane >> 3, c8 = lane & 7;                               \
    const int scol = (c8 ^ srow8) * 8;                                        \
    floatx16 acc[2][2];                                                       \
    _Pragma("unroll")                                                         \
    for (int i = 0; i < 2; ++i)                                               \
        _Pragma("unroll")                                                     \
        for (int j = 0; j < 2; ++j)                                           \
            _Pragma("unroll")                                                 \
            for (int r = 0; r < 16; ++r) acc[i][j][r] = 0.f;                  \
    const unsigned short* pa[4];                                              \
    const unsigned short* pb[4];                                              \
    _Pragma("unroll")                                                         \
    for (int i = 0; i < 4; ++i) {                                             \
        pa[i] = (A_) + (size_t)(bm + i * 32 + wave * 8 + srow8) * (Kdim) + scol; \
        pb[i] = (B_) + (size_t)(bn + i * 32 + wave * 8 + srow8) * (Kdim) + scol; \
    }                                                                         \
    int aoff[2][4], boff[2][4];                                               \
    _Pragma("unroll")                                                         \
    for (int f = 0; f < 2; ++f)                                               \
        _Pragma("unroll")                                                     \
        for (int s = 0; s < 4; ++s) {                                         \
            const int cg = ((s * 2 + hi) ^ (l32 & 7)) * 8;                    \
            aoff[f][s] = (wm + f * 32 + l32) * 64 + cg;                       \
            boff[f][s] = (wn + f * 32 + l32) * 64 + cg;                       \
        }                                                                     \
    for (int k0 = 0; k0 < (Kdim); k0 += 64) {                                 \
        _Pragma("unroll")                                                     \
        for (int i = 0; i < 4; ++i) {                                         \
            __builtin_amdgcn_global_load_lds((const GLOBAL_AS void*)(pa[i] + k0), \
                (LDS_AS void*)(As + i * 2048 + wave * 512), 16, 0, 0);        \
            __builtin_amdgcn_global_load_lds((const GLOBAL_AS void*)(pb[i] + k0), \
                (LDS_AS void*)(Bs + i * 2048 + wave * 512), 16, 0, 0);        \
        }                                                                     \
        __syncthreads();                                                      \
        _Pragma("unroll")                                                     \
        for (int s = 0; s < 4; ++s) {                                         \
            short8 af[2], bf[2];                                              \
            _Pragma("unroll")                                                 \
            for (int f = 0; f < 2; ++f) {                                     \
                af[f] = *(const short8*)&As[aoff[f][s]];                      \
                bf[f] = *(const short8*)&Bs[boff[f][s]];                      \
            }                                                                 \
            _Pragma("unroll")                                                 \
            for (int mi = 0; mi < 2; ++mi)                                    \
                _Pragma("unroll")                                             \
                for (int ni = 0; ni < 2; ++ni)                                \
                    acc[mi][ni] = __builtin_amdgcn_mfma_f32_32x32x16_bf16(    \
                        bf[ni], af[mi], acc[mi][ni], 0, 0, 0);                \
        }                                                                     \
        __syncthreads();                                                      \
    }

// ---------------------------------------------------------------------------
// 128^2 GEMM: MODE 0 plain, MODE 2 exact GELU (fus1/fus2). grid (M/128,N/128).
// ---------------------------------------------------------------------------
template <int MODE>
__global__ __launch_bounds__(256) void gemm_kernel(
    const unsigned short* __restrict__ A,
    const unsigned short* __restrict__ Wt,
    const float* __restrict__ bias,
    unsigned short* __restrict__ C,
    int N, int K)
{
    __shared__ unsigned short As[128 * 64];
    __shared__ unsigned short Bs[128 * 64];
    const int bm = blockIdx.x * 128, bn = blockIdx.y * 128;
    GEMM_CORE(A, Wt, K)

    #pragma unroll
    for (int mi = 0; mi < 2; ++mi) {
        const int m = bm + wm + mi * 32 + l32;
        #pragma unroll
        for (int ni = 0; ni < 2; ++ni) {
            #pragma unroll
            for (int rg = 0; rg < 4; ++rg) {
                const int n0 = bn + wn + ni * 32 + rg * 8 + hi * 4;
                float4 bv = *(const float4*)&bias[n0];
                float v[4];
                #pragma unroll
                for (int r = 0; r < 4; ++r)
                    v[r] = acc[mi][ni][rg * 4 + r] + ((const float*)&bv)[r];
                if (MODE == 2) {
                    #pragma unroll
                    for (int r = 0; r < 4; ++r)
                        v[r] = 0.5f * v[r] * (1.0f + erff(v[r] * 0.70710678118f));
                }
                unsigned short o[4] = {f2bf(v[0]), f2bf(v[1]), f2bf(v[2]), f2bf(v[3])};
                *(uint2*)&C[(size_t)m * N + n0] = *(const uint2*)o;
            }
        }
    }
}

// ===========================================================================
// R3 256x256 deep-pipelined GEMM core (T2+T3+T4+T5), kept for qkv/out where
// the grid fills the chip (768 / 256 blocks). See R3 header comment.
// ===========================================================================
#define G256_DECL(A_, B_, Kdim)                                               \
    const int tid = threadIdx.x;                                              \
    const int wave = tid >> 6, lane = tid & 63;                               \
    const int quad = lane >> 4, l16 = lane & 15;                              \
    const int wr = wave >> 2, wc = wave & 3;                                  \
    const int lrow8 = lane >> 3, lc8 = lane & 7;                              \
    floatx4 acc[8][4];                                                        \
    _Pragma("unroll")                                                         \
    for (int i = 0; i < 8; ++i)                                               \
        _Pragma("unroll")                                                     \
        for (int j = 0; j < 4; ++j) acc[i][j] = (floatx4){0.f, 0.f, 0.f, 0.f}; \
    const unsigned short* sA[4];                                              \
    const unsigned short* sB[4];                                              \
    int ldst[4];                                                              \
    _Pragma("unroll")                                                         \
    for (int h = 0; h < 2; ++h)                                               \
        _Pragma("unroll")                                                     \
        for (int j = 0; j < 2; ++j) {                                         \
            const int r0 = h * 128 + j * 64 + wave * 8;                       \
            const int r = r0 + lrow8;                                         \
            const int cg = lc8 ^ (r & 7);                                     \
            sA[h * 2 + j] = (A_) + (size_t)(bm + r) * (Kdim) + cg * 8;        \
            sB[h * 2 + j] = (B_) + (size_t)(bn + r) * (Kdim) + cg * 8;        \
            ldst[h * 2 + j] = r0 * 64;                                        \
        }

#define G256_STG_A(s_) __builtin_amdgcn_global_load_lds(                      \
    (const GLOBAL_AS void*)(sA[s_] + ko), (LDS_AS void*)(L + cb + ldst[s_]), 16, 0, 0)
#define G256_STG_B(s_) __builtin_amdgcn_global_load_lds(                      \
    (const GLOBAL_AS void*)(sB[s_] + ko), (LDS_AS void*)(L + cb + 16384 + ldst[s_]), 16, 0, 0)

#define G256_LDA(mh_)                                                         \
    _Pragma("unroll")                                                         \
    for (int mi = 0; mi < 4; ++mi) {                                          \
        const int r = (mh_) * 128 + wr * 64 + mi * 16 + l16;                  \
        _Pragma("unroll")                                                     \
        for (int kk = 0; kk < 2; ++kk)                                        \
            afc[mi][kk] = *(const short8*)&L[cb + r * 64 +                    \
                (((kk * 4 + quad) ^ (r & 7)) * 8)];                           \
    }
#define G256_LDB(nh_)                                                         \
    _Pragma("unroll")                                                         \
    for (int nj = 0; nj < 2; ++nj) {                                          \
        const int r = (nh_) * 128 + wc * 32 + nj * 16 + l16;                  \
        _Pragma("unroll")                                                     \
        for (int kk = 0; kk < 2; ++kk)                                        \
            bfr[(nh_) * 2 + nj][kk] = *(const short8*)&L[cb + 16384 + r * 64 +\
                (((kk * 4 + quad) ^ (r & 7)) * 8)];                           \
    }

#define G256_FENCE() do {                                                     \
    asm volatile("s_waitcnt lgkmcnt(0)" ::: "memory");                        \
    __builtin_amdgcn_sched_barrier(0);                                        \
    __builtin_amdgcn_s_barrier(); } while (0)

#define G256_MM(mh_, nb_) do {                                                \
    __builtin_amdgcn_s_setprio(1);                                            \
    _Pragma("unroll")                                                         \
    for (int mi = 0; mi < 4; ++mi)                                            \
        _Pragma("unroll")                                                     \
        for (int nj = 0; nj < 2; ++nj)                                        \
            _Pragma("unroll")                                                 \
            for (int kk = 0; kk < 2; ++kk)                                    \
                acc[(mh_) * 4 + mi][(nb_) + nj] =                             \
                    __builtin_amdgcn_mfma_f32_16x16x32_bf16(                  \
                        bfr[(nb_) + nj][kk], afc[mi][kk],                     \
                        acc[(mh_) * 4 + mi][(nb_) + nj], 0, 0, 0);            \
    __builtin_amdgcn_s_setprio(0); } while (0)

#define G256_CORE(A_, B_, Kdim)                                               \
    G256_DECL(A_, B_, Kdim)                                                   \
    {   /* prologue: stage tile0 -> buf0, tile1 -> buf1 */                    \
        _Pragma("unroll")                                                     \
        for (int s = 0; s < 4; ++s) {                                         \
            __builtin_amdgcn_global_load_lds((const GLOBAL_AS void*)(sA[s]),  \
                (LDS_AS void*)(L + ldst[s]), 16, 0, 0);                       \
            __builtin_amdgcn_global_load_lds((const GLOBAL_AS void*)(sB[s]),  \
                (LDS_AS void*)(L + 16384 + ldst[s]), 16, 0, 0);               \
        }                                                                     \
        _Pragma("unroll")                                                     \
        for (int s = 0; s < 4; ++s) {                                         \
            __builtin_amdgcn_global_load_lds((const GLOBAL_AS void*)(sA[s] + 64), \
                (LDS_AS void*)(L + 32768 + ldst[s]), 16, 0, 0);               \
            __builtin_amdgcn_global_load_lds((const GLOBAL_AS void*)(sB[s] + 64), \
                (LDS_AS void*)(L + 32768 + 16384 + ldst[s]), 16, 0, 0);       \
        }                                                                     \
        asm volatile("s_waitcnt vmcnt(8)" ::: "memory");                      \
        __builtin_amdgcn_s_barrier();                                         \
    }                                                                         \
    short8 afc[4][2];                                                         \
    short8 bfr[4][2];                                                         \
    const int NT = (Kdim) >> 6;                                               \
    for (int t = 0; t < NT; ++t) {                                            \
        const int cb = (t & 1) << 15;                                         \
        const int ko = (t + 2) << 6;                                          \
        const bool stg = (t < NT - 2);                                        \
        /* p1 */                                                              \
        G256_LDA(0)                                                           \
        G256_LDB(0)                                                           \
        G256_FENCE();                                                         \
        G256_MM(0, 0);                                                        \
        /* p2 */                                                              \
        G256_LDB(1)                                                           \
        if (stg) { G256_STG_A(0); G256_STG_A(1); G256_STG_B(0); G256_STG_B(1); } \
        G256_FENCE();                                                         \
        G256_MM(0, 2);                                                        \
        /* p3 */                                                              \
        G256_LDA(1)                                                           \
        if (stg) { G256_STG_B(2); G256_STG_B(3); }                            \
        G256_FENCE();                                                         \
        G256_MM(1, 2);                                                        \
        /* p4 */                                                              \
        if (stg) {                                                            \
            G256_STG_A(2); G256_STG_A(3);                                     \
            asm volatile("s_waitcnt vmcnt(8)" ::: "memory");                  \
        } else {                                                              \
            asm volatile("s_waitcnt vmcnt(0)" ::: "memory");                  \
        }                                                                     \
        __builtin_amdgcn_sched_barrier(0);                                    \
        __builtin_amdgcn_s_barrier();                                         \
        G256_MM(1, 0);                                                        \
    }

// ---------------------------------------------------------------------------
// Merged output-projection GEMM, both streams + residual. grid (32, 8).
// ---------------------------------------------------------------------------
__global__ __launch_bounds__(512, 2) void gemm_out_kernel(
    const unsigned short* __restrict__ A0, const unsigned short* __restrict__ W0,
    const float* __restrict__ bi0, const float* __restrict__ r0, unsigned short* __restrict__ C0,
    const unsigned short* __restrict__ A1, const unsigned short* __restrict__ W1,
    const float* __restrict__ bi1, const float* __restrict__ r1, unsigned short* __restrict__ C1)
{
    __shared__ unsigned short L[65536];
    const int s1 = blockIdx.y >> 2;
    const unsigned short* A = s1 ? A1 : A0;
    const unsigned short* Wt = s1 ? W1 : W0;
    const float* bias = s1 ? bi1 : bi0;
    const float* resid = s1 ? r1 : r0;
    unsigned short* C = s1 ? C1 : C0;
    const int bm = blockIdx.x * 256, bn = (blockIdx.y & 3) * 256;
    G256_CORE(A, Wt, 1024)

    #pragma unroll
    for (int i = 0; i < 8; ++i) {
        const int m = bm + (i >> 2) * 128 + wr * 64 + (i & 3) * 16 + l16;
        #pragma unroll
        for (int j = 0; j < 4; ++j) {
            const int n0 = bn + (j >> 1) * 128 + wc * 32 + (j & 1) * 16 + quad * 4;
            float4 bv = *(const float4*)&bias[n0];
            float4 rv = *(const float4*)&resid[(size_t)m * 1024 + n0];
            float v[4];
            v[0] = acc[i][j][0] + bv.x + rv.x;
            v[1] = acc[i][j][1] + bv.y + rv.y;
            v[2] = acc[i][j][2] + bv.z + rv.z;
            v[3] = acc[i][j][3] + bv.w + rv.w;
            unsigned short o[4] = {f2bf(v[0]), f2bf(v[1]), f2bf(v[2]), f2bf(v[3])};
            *(uint2*)&C[(size_t)m * 1024 + n0] = *(const uint2*)o;
        }
    }
}

// ---------------------------------------------------------------------------
// Merged QKV GEMM, both streams. grid (32, 24). buf 0 (Q): pre-scaled.
// buf 2 (V): per-head transposed layout with d&8 half-swap.
// ---------------------------------------------------------------------------
__global__ __launch_bounds__(512, 2) void gemm_qkv_kernel(
    const unsigned short* __restrict__ At, const unsigned short* __restrict__ Wt3t,
    const float* __restrict__ tb0, const float* __restrict__ tb1, const float* __restrict__ tb2,
    unsigned short* __restrict__ to0, unsigned short* __restrict__ to1, unsigned short* __restrict__ to2,
    const unsigned short* __restrict__ Af, const unsigned short* __restrict__ Wt3f,
    const float* __restrict__ fb0, const float* __restrict__ fb1, const float* __restrict__ fb2,
    unsigned short* __restrict__ fo0, unsigned short* __restrict__ fo1, unsigned short* __restrict__ fo2,
    float scale0)
{
    __shared__ unsigned short L[65536];
    const int str = blockIdx.y >= 12;
    const unsigned short* A = str ? Af : At;
    const unsigned short* Wt = str ? Wt3f : Wt3t;
    const int byy = str ? (blockIdx.y - 12) : blockIdx.y;
    const int buf = byy >> 2;
    const int bn = byy * 256;
    const int cn = (byy & 3) * 256;
    const float* bias = str ? (buf == 0 ? fb0 : (buf == 1 ? fb1 : fb2))
                            : (buf == 0 ? tb0 : (buf == 1 ? tb1 : tb2));
    unsigned short* C = str ? (buf == 0 ? fo0 : (buf == 1 ? fo1 : fo2))
                            : (buf == 0 ? to0 : (buf == 1 ? to1 : to2));
    const float scale = buf == 0 ? scale0 : 1.0f;
    const int bm = blockIdx.x * 256;
    G256_CORE(A, Wt, 1024)

    #pragma unroll
    for (int i = 0; i < 8; ++i) {
        const int m = bm + (i >> 2) * 128 + wr * 64 + (i & 3) * 16 + l16;
        #pragma unroll
        for (int j = 0; j < 4; ++j) {
            const int n0 = cn + (j >> 1) * 128 + wc * 32 + (j & 1) * 16 + quad * 4;
            float4 bv = *(const float4*)&bias[n0];
            unsigned short o[4];
            #pragma unroll
            for (int r = 0; r < 4; ++r)
                o[r] = f2bf((acc[i][j][r] + ((const float*)&bv)[r]) * scale);
            if (buf == 2) {
                const int b = m >> 11, tk = m & 2047;
                const int h = n0 >> 6, d0 = n0 & 63;
                const int tsw = tk ^ ((d0 & 8) ? 4 : 0);
                unsigned short* vb = C + ((size_t)(b * 16 + h) * 64) * 2048 + tsw;
                #pragma unroll
                for (int r = 0; r < 4; ++r) vb[(size_t)(d0 + r) * 2048] = o[r];
            } else {
                *(uint2*)&C[(size_t)m * 1024 + n0] = *(const uint2*)o;
            }
        }
    }
}

// ---------------------------------------------------------------------------
// Merged flash, flat grid 2048, XCD-clustered. 16KB LDS single-buffer +
// cvt_pk P-packing. R5: VGPR diet -- koff/voff precomputed arrays (24 VGPR)
// replaced by per-nt base offsets with nt/dt folded into the ds_read offset
// immediate (Ks[nt*1024+kb], Vs[dt*1024+vb[nt]]): ~18 VGPR saved, aiming to
// restore the 37% occupancy of the 60-VGPR R0 build.
// ---------------------------------------------------------------------------
__global__ __launch_bounds__(256) void flash_kernel(
    const unsigned short* __restrict__ Q0, const unsigned short* __restrict__ K0,
    const unsigned short* __restrict__ V0, unsigned short* __restrict__ O0,
    const unsigned short* __restrict__ Q1, const unsigned short* __restrict__ K1,
    const unsigned short* __restrict__ V1, unsigned short* __restrict__ O1)
{
    __shared__ unsigned short Ks[64 * 64];
    __shared__ unsigned short Vs[64 * 64];

    const int bid = blockIdx.x;
    const int p = (bid & 7) * 16 + (bid >> 7);
    const int qt = (bid >> 3) & 15;
    const int s1 = p >= 64;
    const int rem = p & 63;
    const int b = rem >> 4, h = rem & 15;
    const unsigned short* Q = s1 ? Q1 : Q0;
    const unsigned short* Kmat = s1 ? K1 : K0;
    const unsigned short* Vtp = s1 ? V1 : V0;
    unsigned short* O = s1 ? O1 : O0;
    const int q0 = qt * 128;

    const int tid = threadIdx.x;
    const int wave = tid >> 6, lane = tid & 63;
    const int quad = lane >> 4, l16 = lane & 15;

    const unsigned short* qp = Q + (size_t)(b * 2048 + q0 + wave * 32 + l16) * 1024 + h * 64;
    short8 qf[2][2];
    qf[0][0] = *(const short8*)(qp + quad * 8);
    qf[0][1] = *(const short8*)(qp + 32 + quad * 8);
    qf[1][0] = *(const short8*)(qp + 16 * 1024 + quad * 8);
    qf[1][1] = *(const short8*)(qp + 16 * 1024 + 32 + quad * 8);

    const int srow8 = lane >> 3;
    const int c8 = lane & 7;
    const int rit0 = wave * 16 + srow8;
    const int rit1 = rit0 + 8;
    const int col0 = (c8 ^ (rit0 & 7)) * 8;
    const int col1 = (c8 ^ (rit1 & 7)) * 8;
    const unsigned short* kbase = Kmat + (size_t)b * 2048 * 1024 + h * 64;
    const unsigned short* vbase = Vtp + (size_t)(b * 16 + h) * 64 * 2048;
    unsigned short* lk0 = Ks + (wave * 16) * 64;
    unsigned short* lk1 = lk0 + 8 * 64;
    unsigned short* lv0 = Vs + (wave * 16) * 64;
    unsigned short* lv1 = lv0 + 8 * 64;

    // Base LDS offsets; nt/dt components folded into ds_read offset immediates.
    const int kb0 = l16 * 64 + ((quad ^ (l16 & 7)) * 8);
    const int kb1 = l16 * 64 + (((4 + quad) ^ (l16 & 7)) * 8);
    const int vbq = ((quad & 1) ^ (l16 >> 3)) * 4;
    int vb[4];
    #pragma unroll
    for (int nt = 0; nt < 4; ++nt)
        vb[nt] = l16 * 64 + (((nt * 2 + (quad >> 1)) ^ (l16 & 7)) * 8) + vbq;

    floatx4 oa[2][4], la[2];
    #pragma unroll
    for (int qg = 0; qg < 2; ++qg) {
        la[qg] = (floatx4){0.f, 0.f, 0.f, 0.f};
        #pragma unroll
        for (int dt = 0; dt < 4; ++dt) oa[qg][dt] = (floatx4){0.f, 0.f, 0.f, 0.f};
    }
    const short4v vone = {(short)0x3F80, (short)0x3F80, (short)0x3F80, (short)0x3F80};

    for (int kt = 0; kt < 32; ++kt) {
        const unsigned short* kg0 = kbase + (size_t)(kt * 64 + rit0) * 1024 + col0;
        const unsigned short* kg1 = kbase + (size_t)(kt * 64 + rit1) * 1024 + col1;
        const unsigned short* vg0 = vbase + (size_t)rit0 * 2048 + kt * 64 + col0;
        const unsigned short* vg1 = vbase + (size_t)rit1 * 2048 + kt * 64 + col1;
        __builtin_amdgcn_global_load_lds((const GLOBAL_AS void*)kg0, (LDS_AS void*)lk0, 16, 0, 0);
        __builtin_amdgcn_global_load_lds((const GLOBAL_AS void*)kg1, (LDS_AS void*)lk1, 16, 0, 0);
        __builtin_amdgcn_global_load_lds((const GLOBAL_AS void*)vg0, (LDS_AS void*)lv0, 16, 0, 0);
        __builtin_amdgcn_global_load_lds((const GLOBAL_AS void*)vg1, (LDS_AS void*)lv1, 16, 0, 0);
        __syncthreads();

        short4v pf[2][4];
        #pragma unroll
        for (int nt = 0; nt < 4; ++nt) {
            short8 k0 = *(const short8*)&Ks[nt * 1024 + kb0];
            short8 k1 = *(const short8*)&Ks[nt * 1024 + kb1];
            #pragma unroll
            for (int qg = 0; qg < 2; ++qg) {
                floatx4 s = (floatx4){0.f, 0.f, 0.f, 0.f};
                s = __builtin_amdgcn_mfma_f32_16x16x32_bf16(k0, qf[qg][0], s, 0, 0, 0);
                s = __builtin_amdgcn_mfma_f32_16x16x32_bf16(k1, qf[qg][1], s, 0, 0, 0);
                float p0 = __builtin_amdgcn_exp2f(s[0]);
                float p1 = __builtin_amdgcn_exp2f(s[1]);
                float p2 = __builtin_amdgcn_exp2f(s[2]);
                float p3 = __builtin_amdgcn_exp2f(s[3]);
                union { unsigned u[2]; short4v s4; } pk;
                asm("v_cvt_pk_bf16_f32 %0, %1, %2"
                    : "=v"(pk.u[0]) : "v"(p0), "v"(p1));
                asm("v_cvt_pk_bf16_f32 %0, %1, %2"
                    : "=v"(pk.u[1]) : "v"(p2), "v"(p3));
                pf[qg][nt] = pk.s4;
                la[qg] = __builtin_amdgcn_mfma_f32_16x16x16bf16_1k(vone, pf[qg][nt], la[qg], 0, 0, 0);
            }
        }
        #pragma unroll
        for (int dt = 0; dt < 4; ++dt)
            #pragma unroll
            for (int nt = 0; nt < 4; ++nt) {
                short4v vf = *(const short4v*)&Vs[dt * 1024 + vb[nt]];
                oa[0][dt] = __builtin_amdgcn_mfma_f32_16x16x16bf16_1k(vf, pf[0][nt], oa[0][dt], 0, 0, 0);
                oa[1][dt] = __builtin_amdgcn_mfma_f32_16x16x16bf16_1k(vf, pf[1][nt], oa[1][dt], 0, 0, 0);
            }
        __syncthreads();
    }

    #pragma unroll
    for (int qg = 0; qg < 2; ++qg) {
        const float linv = 1.0f / la[qg][0];
        unsigned short* orow = O + (size_t)(b * 2048 + q0 + wave * 32 + qg * 16 + l16) * 1024 + h * 64;
        #pragma unroll
        for (int dt = 0; dt < 4; ++dt) {
            unsigned short ob[4];
            #pragma unroll
            for (int r = 0; r < 4; ++r) ob[r] = f2bf(oa[qg][dt][r] * linv);
            *(uint2*)(orow + dt * 16 + quad * 4) = *(const uint2*)ob;
        }
    }
}

// ---------------------------------------------------------------------------
// Mid LayerNorm pair (grid 16384)
// ---------------------------------------------------------------------------
__global__ __launch_bounds__(256) void ln2_kernel(
    const unsigned short* __restrict__ in0, const unsigned short* __restrict__ in1,
    unsigned short* __restrict__ out,
    const float* __restrict__ w0, const float* __restrict__ b0,
    const float* __restrict__ w1, const float* __restrict__ b1)
{
    __shared__ float red[8];
    const int sel = blockIdx.x >> 13;
    const int row = blockIdx.x & 8191;
    const unsigned short* in = sel ? in1 : in0;
    const float* w = sel ? w1 : w0;
    const float* bb = sel ? b1 : b0;
    const int tid = threadIdx.x;
    const int wave = tid >> 6, lane = tid & 63;
    uint2 raw = *(const uint2*)(in + (size_t)row * 1024 + tid * 4);
    float v[4];
    v[0] = bf2f((unsigned short)(raw.x & 0xffffu));
    v[1] = bf2f((unsigned short)(raw.x >> 16));
    v[2] = bf2f((unsigned short)(raw.y & 0xffffu));
    v[3] = bf2f((unsigned short)(raw.y >> 16));
    float s = v[0] + v[1] + v[2] + v[3];
    float sq = v[0] * v[0] + v[1] * v[1] + v[2] * v[2] + v[3] * v[3];
    #pragma unroll
    for (int m = 1; m < 64; m <<= 1) { s += __shfl_xor(s, m); sq += __shfl_xor(sq, m); }
    if (lane == 0) { red[wave] = s; red[4 + wave] = sq; }
    __syncthreads();
    s = red[0] + red[1] + red[2] + red[3];
    sq = red[4] + red[5] + red[6] + red[7];
    const float mu = s * (1.0f / 1024.0f);
    const float var = sq * (1.0f / 1024.0f) - mu * mu;
    const float rstd = rsqrtf(var + 1e-5f);
    unsigned short ob[4];
    #pragma unroll
    for (int j = 0; j < 4; ++j)
        ob[j] = f2bf((v[j] - mu) * rstd * w[tid * 4 + j] + bb[tid * 4 + j]);
    *(uint2*)(out + (size_t)row * 2048 + sel * 1024 + tid * 4) = *(uint2*)ob;
}

// ---------------------------------------------------------------------------
// Final LayerNorm -> fp32 d_out (grid 8192)
// ---------------------------------------------------------------------------
__global__ __launch_bounds__(256) void ln_final_kernel(
    const unsigned short* __restrict__ in, float* __restrict__ out,
    const float* __restrict__ w, const float* __restrict__ bias)
{
    __shared__ float red[8];
    const int row = blockIdx.x;
    const int tid = threadIdx.x;
    const int wave = tid >> 6, lane = tid & 63;
    uint2 raw = *(const uint2*)(in + (size_t)row * 1024 + tid * 4);
    float v[4];
    v[0] = bf2f((unsigned short)(raw.x & 0xffffu));
    v[1] = bf2f((unsigned short)(raw.x >> 16));
    v[2] = bf2f((unsigned short)(raw.y & 0xffffu));
    v[3] = bf2f((unsigned short)(raw.y >> 16));
    float s = v[0] + v[1] + v[2] + v[3];
    float sq = v[0] * v[0] + v[1] * v[1] + v[2] * v[2] + v[3] * v[3];
    #pragma unroll
    for (int m = 1; m < 64; m <<= 1) { s += __shfl_xor(s, m); sq += __shfl_xor(sq, m); }
    if (lane == 0) { red[wave] = s; red[4 + wave] = sq; }
    __syncthreads();
    s = red[0] + red[1] + red[2] + red[3];
    sq = red[4] + red[5] + red[6] + red[7];
    const float mu = s * (1.0f / 1024.0f);
    const float var = sq * (1.0f / 1024.0f) - mu * mu;
    const float rstd = rsqrtf(var + 1e-5f);
    float o[4];
    #pragma unroll
    for (int j = 0; j < 4; ++j)
        o[j] = (v[j] - mu) * rstd * w[tid * 4 + j] + bias[tid * 4 + j];
    *(float4*)(out + (size_t)row * 1024 + tid * 4) = (float4){o[0], o[1], o[2], o[3]};
}

// ---------------------------------------------------------------------------
extern "C" void kernel_launch(void* const* d_in, const int* in_sizes, int n_in,
                              void* d_out, int out_size, void* d_ws, size_t ws_size,
                              hipStream_t stream)
{
    (void)in_sizes; (void)n_in; (void)out_size; (void)ws_size;
    const float* temporal = (const float*)d_in[0];
    const float* feature  = (const float*)d_in[1];
    const float* qt_w = (const float*)d_in[2];
    const float* qt_b = (const float*)d_in[3];
    const float* kf_w = (const float*)d_in[4];
    const float* kf_b = (const float*)d_in[5];
    const float* vf_w = (const float*)d_in[6];
    const float* vf_b = (const float*)d_in[7];
    const float* qf_w = (const float*)d_in[8];
    const float* qf_b = (const float*)d_in[9];
    const float* kt_w = (const float*)d_in[10];
    const float* kt_b = (const float*)d_in[11];
    const float* vt_w = (const float*)d_in[12];
    const float* vt_b = (const float*)d_in[13];
    const float* ot_w = (const float*)d_in[14];
    const float* ot_b = (const float*)d_in[15];
    const float* of_w = (const float*)d_in[16];
    const float* of_b = (const float*)d_in[17];
    const float* fus1_w = (const float*)d_in[18];
    const float* fus1_b = (const float*)d_in[19];
    const float* fus2_w = (const float*)d_in[20];
    const float* fus2_b = (const float*)d_in[21];
    const float* ln_fus_w = (const float*)d_in[22];
    const float* ln_fus_b = (const float*)d_in[23];
    const float* ln_t_w = (const float*)d_in[24];
    const float* ln_t_b = (const float*)d_in[25];
    const float* ln_f_w = (const float*)d_in[26];
    const float* ln_f_b = (const float*)d_in[27];

    unsigned short* p = (unsigned short*)d_ws;
    const size_t EW = 1024ull * 1024;
    const size_t ET = 8192ull * 1024;
    unsigned short* WT3t = p;
    unsigned short* WT3f = p + 3 * EW;
    unsigned short* WTot = p + 6 * EW;
    unsigned short* WTof = p + 7 * EW;
    unsigned short* WTf1 = p + 8 * EW;
    unsigned short* WTf2 = p + 10 * EW;
    size_t off = 11 * EW;
    unsigned short* Tb = p + off; off += ET;
    unsigned short* Fb = p + off; off += ET;
    unsigned short* Qt = p + off; off += ET;
    unsigned short* Kt = p + off; off += ET;
    unsigned short* Vt = p + off; off += ET;   // scratch span for comb
    unsigned short* Qf = p + off; off += ET;
    unsigned short* Kf = p + off; off += ET;
    unsigned short* Vf = p + off; off += ET;   // scratch for y2
    unsigned short* VfT = p + off; off += ET;
    unsigned short* VtT = p + off; off += ET;
    unsigned short* attnT = p + off; off += ET;
    unsigned short* attnF = p + off; off += ET;
    unsigned short* yT = Qt;
    unsigned short* yF = Qf;
    unsigned short* comb = Kt;   // spans Kt+Vt: [8192][2048]
    unsigned short* hbuf = Kf;
    unsigned short* y2 = Vf;
    (void)Vt;

    const float SC = 0.125f * 1.4426950408889634f;

    // 0+1) merged prep: weight transposes + token conversion
    {
        WX P;
        const float* srcs[10] = {qt_w, kt_w, vt_w, qf_w, kf_w, vf_w,
                                 ot_w, of_w, fus1_w, fus2_w};
        unsigned long long dsts[10] = {
            0, EW, 2 * EW,
            3 * EW, 4 * EW, 5 * EW,
            6 * EW, 7 * EW, 8 * EW, 10 * EW};
        int cum = 0;
        P.cum[0] = 0;
        for (int i = 0; i < 10; ++i) {
            P.src[i] = srcs[i];
            P.dst[i] = dsts[i];
            P.r64[i] = (i == 8) ? 32 : 16;
            cum += P.r64[i] * 16;
            P.cum[i + 1] = cum;
        }
        prep_kernel<<<cum + 2048, 256, 0, stream>>>(P, p, temporal, feature, Tb, Fb);
    }

    const dim3 gb5(512);
    // 2) merged QKV projections (256^2 deep core), both streams
    gemm_qkv_kernel<<<dim3(32, 24), gb5, 0, stream>>>(
        Tb, WT3t, qt_b, kt_b, vt_b, Qt, Kt, VtT,
        Fb, WT3f, qf_b, kf_b, vf_b, Qf, Kf, VfT, SC);
    // 3) merged flash, both streams, XCD-clustered flat grid
    flash_kernel<<<2048, dim3(256), 0, stream>>>(
        Qt, Kf, VfT, attnT, Qf, Kt, VtT, attnF);
    // 4) merged output projections + residual (256^2 deep core)
    gemm_out_kernel<<<dim3(32, 8), gb5, 0, stream>>>(
        attnT, WTot, ot_b, temporal, yT,
        attnF, WTof, of_b, feature,  yF);
    // 5) mid LayerNorm pair -> comb
    ln2_kernel<<<16384, dim3(256), 0, stream>>>(yT, yF, comb, ln_t_w, ln_t_b, ln_f_w, ln_f_b);
    // 6) fusion MLP (128^2 core -- full grid coverage, R4 lesson)
    gemm_kernel<2><<<dim3(64, 8), dim3(256), 0, stream>>>(comb, WTf1, fus1_b, hbuf, 1024, 2048);
    gemm_kernel<0><<<dim3(64, 8), dim3(256), 0, stream>>>(hbuf, WTf2, fus2_b, y2, 1024, 1024);
    // 7) final LN -> fp32 d_out
    ln_final_kernel<<<8192, dim3(256), 0, stream>>>(y2, (float*)d_out, ln_fus_w, ln_fus_b);
}